// Round 1
// baseline (136.940 us; speedup 1.0000x reference)
//
#include <hip/hip_runtime.h>
#include <hip/hip_bf16.h>

// GravNet: 32 graphs x 256 nodes, IN=64, HID=256, OUT=32, K=20, SPACE=3, PROP=2
// Layer l: s = x@Ws+bs [N,3]; h = x@Wh+bh [N,2]; within-graph kNN(K=20) in s-space;
// agg = sum_k exp(-10 d2) * h[idx]; out = [agg, x] @ Wo + bo; leaky(0.01) on layers 1,2.
// Final output = layer-3 output at nodes {g*256}.

#define NGRAPH 32
#define GN 256           // nodes per graph
#define NTOT (NGRAPH*GN) // 8192
#define KNN 20

// ---------------- s/h projection: one wave per row ----------------
__global__ __launch_bounds__(256) void sh_kernel(
    const float* __restrict__ X, int cin,
    const float* __restrict__ Ws, const float* __restrict__ bs,
    const float* __restrict__ Wh, const float* __restrict__ bh,
    float* __restrict__ s, float* __restrict__ h, int nrows)
{
    int gw = (int)((blockIdx.x * blockDim.x + threadIdx.x) >> 6);
    int lane = threadIdx.x & 63;
    if (gw >= nrows) return;
    float a0 = 0.f, a1 = 0.f, a2 = 0.f, a3 = 0.f, a4 = 0.f;
    const float* xr = X + (size_t)gw * cin;
    for (int c = lane; c < cin; c += 64) {
        float xv = xr[c];
        a0 = fmaf(xv, Ws[c * 3 + 0], a0);
        a1 = fmaf(xv, Ws[c * 3 + 1], a1);
        a2 = fmaf(xv, Ws[c * 3 + 2], a2);
        a3 = fmaf(xv, Wh[c * 2 + 0], a3);
        a4 = fmaf(xv, Wh[c * 2 + 1], a4);
    }
#pragma unroll
    for (int m = 1; m < 64; m <<= 1) {
        a0 += __shfl_xor(a0, m);
        a1 += __shfl_xor(a1, m);
        a2 += __shfl_xor(a2, m);
        a3 += __shfl_xor(a3, m);
        a4 += __shfl_xor(a4, m);
    }
    if (lane == 0) {
        s[gw * 3 + 0] = a0 + bs[0];
        s[gw * 3 + 1] = a1 + bs[1];
        s[gw * 3 + 2] = a2 + bs[2];
        h[gw * 2 + 0] = a3 + bh[0];
        h[gw * 2 + 1] = a4 + bh[1];
    }
}

// ---------------- kNN + weighted aggregation: one wave per row ----------------
// Exact top-20 (smallest d2, ties -> lower index, matching jax.lax.top_k).
__global__ __launch_bounds__(256) void knn_kernel(
    const float* __restrict__ s, const float* __restrict__ h,
    float* __restrict__ agg, int nrows, int row_mult)
{
    int gw = (int)(blockIdx.x * (blockDim.x >> 6) + (threadIdx.x >> 6));
    int lane = threadIdx.x & 63;
    if (gw >= nrows) return;
    int row = gw * row_mult;
    int base = row & ~(GN - 1);

    float s0 = s[row * 3 + 0], s1 = s[row * 3 + 1], s2 = s[row * 3 + 2];
    float s2row = s0 * s0 + s1 * s1 + s2 * s2;

    auto calc = [&](int j) {
        const float* sj = s + (size_t)(base + j) * 3;
        float t0 = sj[0], t1 = sj[1], t2 = sj[2];
        float s2j = t0 * t0 + t1 * t1 + t2 * t2;
        float dot = s0 * t0 + s1 * t1 + s2 * t2;
        float d2 = s2row + s2j - 2.0f * dot;
        return d2 > 0.f ? d2 : 0.f;
    };
    float da = calc(lane);
    float db = calc(lane + 64);
    float dc = calc(lane + 128);
    float dd = calc(lane + 192);

    float acc0 = 0.f, acc1 = 0.f;
#pragma unroll 1
    for (int it = 0; it < KNN; ++it) {
        // local argmin over 4 slots (index = lane + 64*t; ties keep smaller idx)
        float bv = da; int bi = lane;
        if (db < bv) { bv = db; bi = lane + 64; }
        if (dc < bv) { bv = dc; bi = lane + 128; }
        if (dd < bv) { bv = dd; bi = lane + 192; }
        // butterfly argmin across wave, tie -> lower index
#pragma unroll
        for (int m = 1; m < 64; m <<= 1) {
            float ov = __shfl_xor(bv, m);
            int oi = __shfl_xor(bi, m);
            if (ov < bv || (ov == bv && oi < bi)) { bv = ov; bi = oi; }
        }
        float w = __expf(-10.0f * bv);
        if ((bi & 63) == lane) {
            int t = bi >> 6;
            if (t == 0) da = 3.0e38f;
            else if (t == 1) db = 3.0e38f;
            else if (t == 2) dc = 3.0e38f;
            else dd = 3.0e38f;
            const float* hj = h + (size_t)(base + bi) * 2;
            acc0 = fmaf(w, hj[0], acc0);
            acc1 = fmaf(w, hj[1], acc1);
        }
    }
#pragma unroll
    for (int m = 1; m < 64; m <<= 1) {
        acc0 += __shfl_xor(acc0, m);
        acc1 += __shfl_xor(acc1, m);
    }
    if (lane == 0) {
        agg[gw * 2 + 0] = acc0;
        agg[gw * 2 + 1] = acc1;
    }
}

// ---------------- GEMM: C = leaky?([agg|A] @ W + bo) ; W is [(2+K), N] row-major --------
// 64x64 tile, 256 threads, 4x4 per thread, BK=16.
#define BM 64
#define BN 64
#define BKK 16
__global__ __launch_bounds__(256) void gemm_agg_kernel(
    const float* __restrict__ A, const float* __restrict__ agg,
    const float* __restrict__ W, const float* __restrict__ bias,
    float* __restrict__ C, int M, int N, int K, int leaky)
{
    __shared__ float As[BKK][BM];
    __shared__ float Bs[BKK][BN];
    int tid = threadIdx.x;
    int tx = tid & 15, ty = tid >> 4;
    int m0 = blockIdx.x * BM, n0 = blockIdx.y * BN;

    float acc[4][4];
#pragma unroll
    for (int i = 0; i < 4; ++i) {
        int m = m0 + ty * 4 + i;
        float g0 = agg[m * 2 + 0], g1 = agg[m * 2 + 1];
#pragma unroll
        for (int j = 0; j < 4; ++j) {
            int n = n0 + tx * 4 + j;
            acc[i][j] = fmaf(g0, W[n], fmaf(g1, W[N + n], bias[n]));
        }
    }
    const float* Wx = W + 2 * N;

    for (int k0 = 0; k0 < K; k0 += BKK) {
        {
            int r = tid >> 2, c = (tid & 3) * 4;
            float4 av = *reinterpret_cast<const float4*>(&A[(size_t)(m0 + r) * K + k0 + c]);
            As[c + 0][r] = av.x; As[c + 1][r] = av.y; As[c + 2][r] = av.z; As[c + 3][r] = av.w;
        }
        {
            int r = tid >> 4, c = (tid & 15) * 4;
            float4 bv = *reinterpret_cast<const float4*>(&Wx[(size_t)(k0 + r) * N + n0 + c]);
            *reinterpret_cast<float4*>(&Bs[r][c]) = bv;
        }
        __syncthreads();
#pragma unroll
        for (int k = 0; k < BKK; ++k) {
            float4 a4 = *reinterpret_cast<const float4*>(&As[k][ty * 4]);
            float4 b4 = *reinterpret_cast<const float4*>(&Bs[k][tx * 4]);
            float av[4] = {a4.x, a4.y, a4.z, a4.w};
            float bv[4] = {b4.x, b4.y, b4.z, b4.w};
#pragma unroll
            for (int i = 0; i < 4; ++i)
#pragma unroll
                for (int j = 0; j < 4; ++j)
                    acc[i][j] = fmaf(av[i], bv[j], acc[i][j]);
        }
        __syncthreads();
    }
#pragma unroll
    for (int i = 0; i < 4; ++i) {
        int m = m0 + ty * 4 + i;
#pragma unroll
        for (int j = 0; j < 4; ++j) {
            int n = n0 + tx * 4 + j;
            float v = acc[i][j];
            if (leaky) v = v >= 0.f ? v : 0.01f * v;
            C[(size_t)m * N + n] = v;
        }
    }
}

// ---------------- final layer-3 linear on the 32 surviving rows ----------------
// out[g][o] = sum_c h2[g*256][c]*Wo3[2+c][o] + agg3[g]·Wo3[0:2][o] + bo3[o]
__global__ __launch_bounds__(256) void final_kernel(
    const float* __restrict__ h2, const float* __restrict__ agg3,
    const float* __restrict__ Wo, const float* __restrict__ bo,
    float* __restrict__ out)
{
    int idx = blockIdx.x * blockDim.x + threadIdx.x;  // 0..1023
    int g = idx >> 5, o = idx & 31;
    float acc = fmaf(agg3[g * 2 + 0], Wo[o], fmaf(agg3[g * 2 + 1], Wo[32 + o], bo[o]));
    const float* xr = h2 + (size_t)(g * GN) * 256;
#pragma unroll 8
    for (int c = 0; c < 256; ++c)
        acc = fmaf(xr[c], Wo[(2 + c) * 32 + o], acc);
    out[idx] = acc;
}

extern "C" void kernel_launch(void* const* d_in, const int* in_sizes, int n_in,
                              void* d_out, int out_size, void* d_ws, size_t ws_size,
                              hipStream_t stream) {
    const float* X   = (const float*)d_in[0];
    // d_in[1] = batch (int32) — structure is known (contiguous 256-node graphs), unused.
    const float* Ws1 = (const float*)d_in[2];  const float* bs1 = (const float*)d_in[3];
    const float* Wh1 = (const float*)d_in[4];  const float* bh1 = (const float*)d_in[5];
    const float* Wo1 = (const float*)d_in[6];  const float* bo1 = (const float*)d_in[7];
    const float* Ws2 = (const float*)d_in[8];  const float* bs2 = (const float*)d_in[9];
    const float* Wh2 = (const float*)d_in[10]; const float* bh2 = (const float*)d_in[11];
    const float* Wo2 = (const float*)d_in[12]; const float* bo2 = (const float*)d_in[13];
    const float* Ws3 = (const float*)d_in[14]; const float* bs3 = (const float*)d_in[15];
    const float* Wh3 = (const float*)d_in[16]; const float* bh3 = (const float*)d_in[17];
    const float* Wo3 = (const float*)d_in[18]; const float* bo3 = (const float*)d_in[19];

    float* h1   = (float*)d_ws;                 // 8192*256
    float* h2   = h1 + (size_t)NTOT * 256;      // 8192*256
    float* sbuf = h2 + (size_t)NTOT * 256;      // 8192*3
    float* hp   = sbuf + (size_t)NTOT * 3;      // 8192*2
    float* aggb = hp + (size_t)NTOT * 2;        // 8192*2

    // ---- layer 1 (cin=64) ----
    sh_kernel<<<2048, 256, 0, stream>>>(X, 64, Ws1, bs1, Wh1, bh1, sbuf, hp, NTOT);
    knn_kernel<<<2048, 256, 0, stream>>>(sbuf, hp, aggb, NTOT, 1);
    gemm_agg_kernel<<<dim3(NTOT / BM, 256 / BN), 256, 0, stream>>>(X, aggb, Wo1, bo1, h1,
                                                                   NTOT, 256, 64, 1);
    // ---- layer 2 (cin=256) ----
    sh_kernel<<<2048, 256, 0, stream>>>(h1, 256, Ws2, bs2, Wh2, bh2, sbuf, hp, NTOT);
    knn_kernel<<<2048, 256, 0, stream>>>(sbuf, hp, aggb, NTOT, 1);
    gemm_agg_kernel<<<dim3(NTOT / BM, 256 / BN), 256, 0, stream>>>(h1, aggb, Wo2, bo2, h2,
                                                                   NTOT, 256, 256, 1);
    // ---- layer 3 (cin=256, only rows g*256 needed downstream) ----
    sh_kernel<<<2048, 256, 0, stream>>>(h2, 256, Ws3, bs3, Wh3, bh3, sbuf, hp, NTOT);
    knn_kernel<<<8, 256, 0, stream>>>(sbuf, hp, aggb, NGRAPH, GN);
    final_kernel<<<4, 256, 0, stream>>>(h2, aggb, Wo3, bo3, (float*)d_out);
}

// Round 2
// 120.753 us; speedup vs baseline: 1.1341x; 1.1341x over previous
//
#include <hip/hip_runtime.h>
#include <hip/hip_bf16.h>

// GravNet: 32 graphs x 256 nodes, IN=64, HID=256, OUT=32, K=20, SPACE=3, PROP=2
// Per layer: s=x@Ws+bs [N,3]; h=x@Wh+bh [N,2]; within-graph kNN(20) on s; agg=sum exp(-10 d2)*h;
// out = [agg,x]@Wo+bo; leaky(0.01) on layers 1,2. Output = layer-3 rows {g*256}.
// GEMMs ([x]@Wo_x part) run as split-bf16 MFMA (hi/lo, 3 products) == fp32 precision.

#define NGRAPH 32
#define GN 256
#define NTOT (NGRAPH*GN) // 8192
#define KNN 20

typedef __attribute__((ext_vector_type(8))) short bf16x8;
typedef __attribute__((ext_vector_type(4))) float f32x4;

__device__ __forceinline__ ushort f2bf(float x) {
    union { float f; unsigned u; } a; a.f = x;
    unsigned r = a.u + 0x7FFFu + ((a.u >> 16) & 1u);   // RNE
    return (ushort)(r >> 16);
}
__device__ __forceinline__ float bf2f(ushort h) {
    union { unsigned u; float f; } b; b.u = ((unsigned)h) << 16;
    return b.f;
}

// ---------------- weight prep: Wo[2+c][n] -> Wt[n][c] split into bf16 hi/lo ----------------
__global__ __launch_bounds__(256) void prep_kernel(
    const float* __restrict__ Wo1, const float* __restrict__ Wo2,
    ushort* __restrict__ Wt1hi, ushort* __restrict__ Wt1lo,
    ushort* __restrict__ Wt2hi, ushort* __restrict__ Wt2lo)
{
    int t = blockIdx.x * 256 + threadIdx.x;   // 81920 threads
    if (t < 65536) {
        int n = t >> 8, c = t & 255;
        float v = Wo2[(size_t)(2 + c) * 256 + n];
        ushort hi = f2bf(v);
        Wt2hi[n * 256 + c] = hi;
        Wt2lo[n * 256 + c] = f2bf(v - bf2f(hi));
    } else {
        int u = t - 65536;
        int n = u >> 6, c = u & 63;
        float v = Wo1[(size_t)(2 + c) * 256 + n];
        ushort hi = f2bf(v);
        Wt1hi[n * 64 + c] = hi;
        Wt1lo[n * 64 + c] = f2bf(v - bf2f(hi));
    }
}

// ---------------- s/h projection: one wave per row, float4 loads ----------------
__global__ __launch_bounds__(256) void sh_kernel(
    const float* __restrict__ X, int cin,
    const float* __restrict__ Ws, const float* __restrict__ bs,
    const float* __restrict__ Wh, const float* __restrict__ bh,
    float* __restrict__ s, float* __restrict__ h, int nrows)
{
    int gw = (int)((blockIdx.x * blockDim.x + threadIdx.x) >> 6);
    int lane = threadIdx.x & 63;
    if (gw >= nrows) return;
    float a0 = 0.f, a1 = 0.f, a2 = 0.f, a3 = 0.f, a4 = 0.f;
    const float* xr = X + (size_t)gw * cin;
    for (int c0 = lane * 4; c0 < cin; c0 += 256) {
        float4 v = *reinterpret_cast<const float4*>(&xr[c0]);
        float xv[4] = {v.x, v.y, v.z, v.w};
#pragma unroll
        for (int j = 0; j < 4; ++j) {
            int c = c0 + j;
            a0 = fmaf(xv[j], Ws[c * 3 + 0], a0);
            a1 = fmaf(xv[j], Ws[c * 3 + 1], a1);
            a2 = fmaf(xv[j], Ws[c * 3 + 2], a2);
            a3 = fmaf(xv[j], Wh[c * 2 + 0], a3);
            a4 = fmaf(xv[j], Wh[c * 2 + 1], a4);
        }
    }
#pragma unroll
    for (int m = 1; m < 64; m <<= 1) {
        a0 += __shfl_xor(a0, m);
        a1 += __shfl_xor(a1, m);
        a2 += __shfl_xor(a2, m);
        a3 += __shfl_xor(a3, m);
        a4 += __shfl_xor(a4, m);
    }
    if (lane == 0) {
        s[gw * 3 + 0] = a0 + bs[0];
        s[gw * 3 + 1] = a1 + bs[1];
        s[gw * 3 + 2] = a2 + bs[2];
        h[gw * 2 + 0] = a3 + bh[0];
        h[gw * 2 + 1] = a4 + bh[1];
    }
}

// ---------------- kNN + weighted aggregation: one wave per row, u64 packed keys ----------------
// key = (f32bits(d2) << 8) | idx : exact d2-asc, idx-asc tie-break (matches jax.lax.top_k).
__global__ __launch_bounds__(256) void knn_kernel(
    const float* __restrict__ s, const float* __restrict__ h,
    float* __restrict__ agg, int nrows, int row_mult)
{
    int gw = (int)(blockIdx.x * (blockDim.x >> 6) + (threadIdx.x >> 6));
    int lane = threadIdx.x & 63;
    if (gw >= nrows) return;
    int row = gw * row_mult;
    int base = row & ~(GN - 1);

    float s0 = s[row * 3 + 0], s1 = s[row * 3 + 1], s2 = s[row * 3 + 2];
    float s2row = s0 * s0 + s1 * s1 + s2 * s2;

    auto calc = [&](int j) {
        const float* sj = s + (size_t)(base + j) * 3;
        float t0 = sj[0], t1 = sj[1], t2 = sj[2];
        float s2j = t0 * t0 + t1 * t1 + t2 * t2;
        float dot = s0 * t0 + s1 * t1 + s2 * t2;
        float d2 = s2row + s2j - 2.0f * dot;
        return d2 > 0.f ? d2 : 0.f;
    };
    auto pack = [&](float d2, int j) {
        return ((unsigned long long)__float_as_uint(d2) << 8) | (unsigned)j;
    };
    unsigned long long ka = pack(calc(lane),        lane);
    unsigned long long kb = pack(calc(lane + 64),   lane + 64);
    unsigned long long kc = pack(calc(lane + 128),  lane + 128);
    unsigned long long kd = pack(calc(lane + 192),  lane + 192);

    float acc0 = 0.f, acc1 = 0.f;
#pragma unroll 1
    for (int it = 0; it < KNN; ++it) {
        unsigned long long m1 = ka < kb ? ka : kb;
        unsigned long long m2 = kc < kd ? kc : kd;
        unsigned long long lm = m1 < m2 ? m1 : m2;
        unsigned long long g = lm;
#pragma unroll
        for (int m = 1; m < 64; m <<= 1) {
            unsigned long long o = __shfl_xor(g, m);
            g = o < g ? o : g;
        }
        if (lm == g) {  // unique winner (idx embedded in key)
            int j = (int)(g & 255u);
            int t = j >> 6;
            if (t == 0) ka = ~0ull;
            else if (t == 1) kb = ~0ull;
            else if (t == 2) kc = ~0ull;
            else kd = ~0ull;
            float d2 = __uint_as_float((unsigned)(g >> 8));
            float w = __expf(-10.0f * d2);
            const float* hj = h + (size_t)(base + j) * 2;
            acc0 = fmaf(w, hj[0], acc0);
            acc1 = fmaf(w, hj[1], acc1);
        }
    }
#pragma unroll
    for (int m = 1; m < 64; m <<= 1) {
        acc0 += __shfl_xor(acc0, m);
        acc1 += __shfl_xor(acc1, m);
    }
    if (lane == 0) {
        agg[gw * 2 + 0] = acc0;
        agg[gw * 2 + 1] = acc1;
    }
}

// ---------------- MFMA split-bf16 GEMM: C = leaky?(A@Wx + agg@Wa + bias) ----------------
// A fp32 [M][K]; Wt hi/lo bf16 [256][K] (pre-transposed); Wfull fp32 [K+2][256] for agg rows.
// Block 512 thr (8 waves, 2m x 4n), BM=64, BN=128, BK=64. Grid (M/64, 2) = 256 blocks.
__global__ __launch_bounds__(512) void gemm_mfma_kernel(
    const float* __restrict__ A, int K,
    const ushort* __restrict__ Wthi, const ushort* __restrict__ Wtlo,
    const float* __restrict__ Wfull, const float* __restrict__ bias,
    const float* __restrict__ agg,
    float* __restrict__ C, int leaky)
{
    __shared__ ushort Ahi[64 * 64], Alo[64 * 64], Bhi[128 * 64], Blo[128 * 64];
    const int tid = threadIdx.x;
    const int lane = tid & 63, wid = tid >> 6;
    const int wm = wid >> 2, wn = wid & 3;          // 2 x 4 wave grid, each 32x32 out
    const int m0 = blockIdx.x * 64, n0 = blockIdx.y * 128;

    f32x4 acc[2][2];
#pragma unroll
    for (int mi = 0; mi < 2; ++mi)
#pragma unroll
        for (int ni = 0; ni < 2; ++ni)
            acc[mi][ni] = (f32x4){0.f, 0.f, 0.f, 0.f};

    for (int k0 = 0; k0 < K; k0 += 64) {
        __syncthreads();
        // stage A: 64 rows x 64 k fp32 -> hi/lo bf16, XOR-swizzled
#pragma unroll
        for (int i = 0; i < 2; ++i) {
            int lin = tid + i * 512;
            int row = lin >> 4, c4 = (lin & 15) * 4;
            float4 v = *reinterpret_cast<const float4*>(&A[(size_t)(m0 + row) * K + k0 + c4]);
            int idx = (row * 64 + c4) ^ ((row & 7) << 3);
            ushort4 hi, lo;
            hi.x = f2bf(v.x); lo.x = f2bf(v.x - bf2f(hi.x));
            hi.y = f2bf(v.y); lo.y = f2bf(v.y - bf2f(hi.y));
            hi.z = f2bf(v.z); lo.z = f2bf(v.z - bf2f(hi.z));
            hi.w = f2bf(v.w); lo.w = f2bf(v.w - bf2f(hi.w));
            *reinterpret_cast<ushort4*>(&Ahi[idx]) = hi;
            *reinterpret_cast<ushort4*>(&Alo[idx]) = lo;
        }
        // stage B: straight copy of pre-split Wt [128 n][64 k], XOR-swizzled
#pragma unroll
        for (int i = 0; i < 2; ++i) {
            int lin = tid + i * 512;
            int row = lin >> 3, c8 = (lin & 7) * 8;
            int idx = (row * 64 + c8) ^ ((row & 7) << 3);
            size_t g = (size_t)(n0 + row) * K + k0 + c8;
            *reinterpret_cast<float4*>(&Bhi[idx]) = *reinterpret_cast<const float4*>(&Wthi[g]);
            *reinterpret_cast<float4*>(&Blo[idx]) = *reinterpret_cast<const float4*>(&Wtlo[g]);
        }
        __syncthreads();
#pragma unroll
        for (int kc = 0; kc < 64; kc += 32) {
            int kofs = kc + (lane >> 4) * 8;
            bf16x8 ah[2], al[2], bh[2], bl[2];
#pragma unroll
            for (int mi = 0; mi < 2; ++mi) {
                int r = wm * 32 + mi * 16 + (lane & 15);
                int idx = (r * 64 + kofs) ^ ((r & 7) << 3);
                ah[mi] = *reinterpret_cast<const bf16x8*>(&Ahi[idx]);
                al[mi] = *reinterpret_cast<const bf16x8*>(&Alo[idx]);
            }
#pragma unroll
            for (int ni = 0; ni < 2; ++ni) {
                int r = wn * 32 + ni * 16 + (lane & 15);
                int idx = (r * 64 + kofs) ^ ((r & 7) << 3);
                bh[ni] = *reinterpret_cast<const bf16x8*>(&Bhi[idx]);
                bl[ni] = *reinterpret_cast<const bf16x8*>(&Blo[idx]);
            }
#pragma unroll
            for (int mi = 0; mi < 2; ++mi)
#pragma unroll
                for (int ni = 0; ni < 2; ++ni) {
                    acc[mi][ni] = __builtin_amdgcn_mfma_f32_16x16x32_bf16(ah[mi], bh[ni], acc[mi][ni], 0, 0, 0);
                    acc[mi][ni] = __builtin_amdgcn_mfma_f32_16x16x32_bf16(ah[mi], bl[ni], acc[mi][ni], 0, 0, 0);
                    acc[mi][ni] = __builtin_amdgcn_mfma_f32_16x16x32_bf16(al[mi], bh[ni], acc[mi][ni], 0, 0, 0);
                }
        }
    }
    // epilogue: + agg@Wa + bias, leaky, store. C/D map: col=lane&15, row=(lane>>4)*4+reg.
#pragma unroll
    for (int ni = 0; ni < 2; ++ni) {
        int n = n0 + wn * 32 + ni * 16 + (lane & 15);
        float w0 = Wfull[n], w1 = Wfull[256 + n], bz = bias[n];
#pragma unroll
        for (int mi = 0; mi < 2; ++mi) {
            int mb = m0 + wm * 32 + mi * 16 + ((lane >> 4) << 2);
#pragma unroll
            for (int r = 0; r < 4; ++r) {
                int m = mb + r;
                float v = acc[mi][ni][r] + fmaf(agg[m * 2 + 0], w0, fmaf(agg[m * 2 + 1], w1, bz));
                if (leaky) v = v >= 0.f ? v : 0.01f * v;
                C[(size_t)m * 256 + n] = v;
            }
        }
    }
}

// ---------------- final layer-3 linear on the 32 surviving rows ----------------
__global__ __launch_bounds__(256) void final_kernel(
    const float* __restrict__ h2, const float* __restrict__ agg3,
    const float* __restrict__ Wo, const float* __restrict__ bo,
    float* __restrict__ out)
{
    int idx = blockIdx.x * blockDim.x + threadIdx.x;  // 0..1023
    int g = idx >> 5, o = idx & 31;
    float acc = fmaf(agg3[g * 2 + 0], Wo[o], fmaf(agg3[g * 2 + 1], Wo[32 + o], bo[o]));
    const float* xr = h2 + (size_t)(g * GN) * 256;
#pragma unroll 8
    for (int c = 0; c < 256; ++c)
        acc = fmaf(xr[c], Wo[(2 + c) * 32 + o], acc);
    out[idx] = acc;
}

extern "C" void kernel_launch(void* const* d_in, const int* in_sizes, int n_in,
                              void* d_out, int out_size, void* d_ws, size_t ws_size,
                              hipStream_t stream) {
    const float* X   = (const float*)d_in[0];
    const float* Ws1 = (const float*)d_in[2];  const float* bs1 = (const float*)d_in[3];
    const float* Wh1 = (const float*)d_in[4];  const float* bh1 = (const float*)d_in[5];
    const float* Wo1 = (const float*)d_in[6];  const float* bo1 = (const float*)d_in[7];
    const float* Ws2 = (const float*)d_in[8];  const float* bs2 = (const float*)d_in[9];
    const float* Wh2 = (const float*)d_in[10]; const float* bh2 = (const float*)d_in[11];
    const float* Wo2 = (const float*)d_in[12]; const float* bo2 = (const float*)d_in[13];
    const float* Ws3 = (const float*)d_in[14]; const float* bs3 = (const float*)d_in[15];
    const float* Wh3 = (const float*)d_in[16]; const float* bh3 = (const float*)d_in[17];
    const float* Wo3 = (const float*)d_in[18]; const float* bo3 = (const float*)d_in[19];

    float* h1   = (float*)d_ws;                  // 8192*256
    float* h2   = h1 + (size_t)NTOT * 256;       // 8192*256
    float* sbuf = h2 + (size_t)NTOT * 256;       // 8192*3
    float* hp   = sbuf + (size_t)NTOT * 3;       // 8192*2
    float* aggb = hp + (size_t)NTOT * 2;         // 8192*2
    ushort* Wt1hi = (ushort*)(aggb + (size_t)NTOT * 2);  // 256*64
    ushort* Wt1lo = Wt1hi + 256 * 64;
    ushort* Wt2hi = Wt1lo + 256 * 64;            // 256*256
    ushort* Wt2lo = Wt2hi + 256 * 256;

    prep_kernel<<<320, 256, 0, stream>>>(Wo1, Wo2, Wt1hi, Wt1lo, Wt2hi, Wt2lo);

    // ---- layer 1 (cin=64) ----
    sh_kernel<<<2048, 256, 0, stream>>>(X, 64, Ws1, bs1, Wh1, bh1, sbuf, hp, NTOT);
    knn_kernel<<<2048, 256, 0, stream>>>(sbuf, hp, aggb, NTOT, 1);
    gemm_mfma_kernel<<<dim3(NTOT / 64, 2), 512, 0, stream>>>(X, 64, Wt1hi, Wt1lo,
                                                             Wo1, bo1, aggb, h1, 1);
    // ---- layer 2 (cin=256) ----
    sh_kernel<<<2048, 256, 0, stream>>>(h1, 256, Ws2, bs2, Wh2, bh2, sbuf, hp, NTOT);
    knn_kernel<<<2048, 256, 0, stream>>>(sbuf, hp, aggb, NTOT, 1);
    gemm_mfma_kernel<<<dim3(NTOT / 64, 2), 512, 0, stream>>>(h1, 256, Wt2hi, Wt2lo,
                                                             Wo2, bo2, aggb, h2, 1);
    // ---- layer 3 (cin=256, only rows g*256 needed) ----
    sh_kernel<<<2048, 256, 0, stream>>>(h2, 256, Ws3, bs3, Wh3, bh3, sbuf, hp, NTOT);
    knn_kernel<<<8, 256, 0, stream>>>(sbuf, hp, aggb, NGRAPH, GN);
    final_kernel<<<4, 256, 0, stream>>>(h2, aggb, Wo3, bo3, (float*)d_out);
}

// Round 3
// 102.800 us; speedup vs baseline: 1.3321x; 1.1746x over previous
//
#include <hip/hip_runtime.h>
#include <hip/hip_bf16.h>

// GravNet: 32 graphs x 256 nodes, IN=64, HID=256, OUT=32, K=20, SPACE=3, PROP=2
// 6-launch pipeline:
//  K1 k_front   : sh1 (wave/row) | weight split/transpose | bias-init of s/h bufs (grid-split)
//  K2 knn       : layer-1 kNN+aggregate (wave/row, u64 keys, early exit)
//  K3 gemm_fused: h1 = leaky([agg,X]@Wo1+bo1)  + fused s2/h2 partials (LDS C-tile -> global atomics)
//  K4 knn       : layer-2 kNN+aggregate
//  K5 gemm_fused: h2(rows g*256 only) + fused s3/h3 partials
//  K6 knn3_final: per-graph kNN of row g*256 + final 258->32 matvec
// GEMM x-part runs as split-bf16 MFMA (hi/lo, 3 products) == fp32 precision.

#define NGRAPH 32
#define GN 256
#define NTOT (NGRAPH*GN) // 8192
#define KNN 20

typedef __attribute__((ext_vector_type(8))) short bf16x8;
typedef __attribute__((ext_vector_type(4))) float f32x4;

__device__ __forceinline__ ushort f2bf(float x) {
    union { float f; unsigned u; } a; a.f = x;
    unsigned r = a.u + 0x7FFFu + ((a.u >> 16) & 1u);   // RNE
    return (ushort)(r >> 16);
}
__device__ __forceinline__ float bf2f(ushort h) {
    union { unsigned u; float f; } b; b.u = ((unsigned)h) << 16;
    return b.f;
}

// ---------------- K1: sh1 | prep | init (grid-split) ----------------
__global__ __launch_bounds__(256) void k_front(
    const float* __restrict__ X,
    const float* __restrict__ Ws1, const float* __restrict__ bs1,
    const float* __restrict__ Wh1, const float* __restrict__ bh1,
    const float* __restrict__ Wo1, const float* __restrict__ Wo2,
    const float* __restrict__ bs2, const float* __restrict__ bh2,
    const float* __restrict__ bs3, const float* __restrict__ bh3,
    ushort* __restrict__ Wt1hi, ushort* __restrict__ Wt1lo,
    ushort* __restrict__ Wt2hi, ushort* __restrict__ Wt2lo,
    float* __restrict__ s1, float* __restrict__ h1p,
    float* __restrict__ s2, float* __restrict__ h2p,
    float* __restrict__ s3, float* __restrict__ h3p)
{
    int b = blockIdx.x, tid = threadIdx.x;
    if (b < 2048) {                       // ---- sh1: 4 rows/block, cin=64
        int gw = b * 4 + (tid >> 6);
        int lane = tid & 63;
        float xv = X[(size_t)gw * 64 + lane];
        float a0 = xv * Ws1[lane * 3 + 0];
        float a1 = xv * Ws1[lane * 3 + 1];
        float a2 = xv * Ws1[lane * 3 + 2];
        float a3 = xv * Wh1[lane * 2 + 0];
        float a4 = xv * Wh1[lane * 2 + 1];
#pragma unroll
        for (int m = 1; m < 64; m <<= 1) {
            a0 += __shfl_xor(a0, m); a1 += __shfl_xor(a1, m); a2 += __shfl_xor(a2, m);
            a3 += __shfl_xor(a3, m); a4 += __shfl_xor(a4, m);
        }
        if (lane == 0) {
            s1[gw * 3 + 0] = a0 + bs1[0];
            s1[gw * 3 + 1] = a1 + bs1[1];
            s1[gw * 3 + 2] = a2 + bs1[2];
            h1p[gw * 2 + 0] = a3 + bh1[0];
            h1p[gw * 2 + 1] = a4 + bh1[1];
        }
    } else if (b < 2368) {                // ---- prep: Wo[2+c][n] -> Wt[n][c] hi/lo
        int t = (b - 2048) * 256 + tid;
        if (t < 65536) {
            int n = t >> 8, c = t & 255;
            float v = Wo2[(size_t)(2 + c) * 256 + n];
            ushort hi = f2bf(v);
            Wt2hi[n * 256 + c] = hi;
            Wt2lo[n * 256 + c] = f2bf(v - bf2f(hi));
        } else {
            int u = t - 65536;
            int n = u >> 6, c = u & 63;
            float v = Wo1[(size_t)(2 + c) * 256 + n];
            ushort hi = f2bf(v);
            Wt1hi[n * 64 + c] = hi;
            Wt1lo[n * 64 + c] = f2bf(v - bf2f(hi));
        }
    } else {                              // ---- init s2/h2/s3/h3 with biases
        int u = (b - 2368) * 256 + tid;   // 0..81919
        if (u < 24576)      s2[u] = bs2[u % 3];
        else if (u < 40960) { int w = u - 24576; h2p[w] = bh2[w & 1]; }
        else if (u < 65536) { int w = u - 40960; s3[w] = bs3[w % 3]; }
        else                { int w = u - 65536; h3p[w] = bh3[w & 1]; }
    }
}

// ---------------- kNN + weighted aggregation core (one wave per row) ----------------
// key = (f32bits(d2) << 8) | idx : exact d2-asc, idx-asc tie-break (matches jax.lax.top_k).
// Early exit when winner d2 > 2.0 (w < 2e-9 -> residual < 1e-6, way below threshold).
__device__ __forceinline__ void knn_row_agg(
    const float* __restrict__ s, const float* __restrict__ h,
    int base, int row, int lane, float& out0, float& out1)
{
    float s0 = s[row * 3 + 0], s1 = s[row * 3 + 1], s2 = s[row * 3 + 2];
    float s2row = s0 * s0 + s1 * s1 + s2 * s2;
    auto calc = [&](int j) {
        const float* sj = s + (size_t)(base + j) * 3;
        float t0 = sj[0], t1 = sj[1], t2 = sj[2];
        float s2j = t0 * t0 + t1 * t1 + t2 * t2;
        float dot = s0 * t0 + s1 * t1 + s2 * t2;
        float d2 = s2row + s2j - 2.0f * dot;
        return d2 > 0.f ? d2 : 0.f;
    };
    auto pack = [&](float d2, int j) {
        return ((unsigned long long)__float_as_uint(d2) << 8) | (unsigned)j;
    };
    unsigned long long ka = pack(calc(lane),        lane);
    unsigned long long kb = pack(calc(lane + 64),   lane + 64);
    unsigned long long kc = pack(calc(lane + 128),  lane + 128);
    unsigned long long kd = pack(calc(lane + 192),  lane + 192);

    float acc0 = 0.f, acc1 = 0.f;
#pragma unroll 1
    for (int it = 0; it < KNN; ++it) {
        unsigned long long m1 = ka < kb ? ka : kb;
        unsigned long long m2 = kc < kd ? kc : kd;
        unsigned long long lm = m1 < m2 ? m1 : m2;
        unsigned long long g = lm;
#pragma unroll
        for (int m = 1; m < 64; m <<= 1) {
            unsigned long long o = __shfl_xor(g, m);
            g = o < g ? o : g;
        }
        float d2 = __uint_as_float((unsigned)(g >> 8));
        if (d2 > 2.0f) break;            // wave-uniform: residual weights < 2e-9
        if (lm == g) {                   // unique winner (idx embedded)
            int j = (int)(g & 255u);
            int t = j >> 6;
            if (t == 0) ka = ~0ull;
            else if (t == 1) kb = ~0ull;
            else if (t == 2) kc = ~0ull;
            else kd = ~0ull;
            float w = __expf(-10.0f * d2);
            const float* hj = h + (size_t)(base + j) * 2;
            acc0 = fmaf(w, hj[0], acc0);
            acc1 = fmaf(w, hj[1], acc1);
        }
    }
#pragma unroll
    for (int m = 1; m < 64; m <<= 1) {
        acc0 += __shfl_xor(acc0, m);
        acc1 += __shfl_xor(acc1, m);
    }
    out0 = acc0; out1 = acc1;
}

__global__ __launch_bounds__(256) void knn_kernel(
    const float* __restrict__ s, const float* __restrict__ h,
    float* __restrict__ agg)
{
    int gw = (int)(blockIdx.x * 4 + (threadIdx.x >> 6));
    int lane = threadIdx.x & 63;
    float a0, a1;
    knn_row_agg(s, h, gw & ~(GN - 1), gw, lane, a0, a1);
    if (lane == 0) {
        agg[gw * 2 + 0] = a0;
        agg[gw * 2 + 1] = a1;
    }
}

// ---------------- MFMA split-bf16 GEMM + fused next-layer s/h projection ----------------
// C = leaky([A|agg] @ W + bias); C-tile parked in LDS (over B bufs); phase2 dots it with
// Wsn/Whn and atomicAdds into bias-pre-initialized s_out/h_out.
// Block 512 thr (8 waves, 2m x 4n), BM=64, BN=128, BK=64. Grid (M/64, 2).
__global__ __launch_bounds__(512) void gemm_fused(
    const float* __restrict__ A, int K,
    const ushort* __restrict__ Wthi, const ushort* __restrict__ Wtlo,
    const float* __restrict__ Wfull, const float* __restrict__ bias,
    const float* __restrict__ agg,
    float* __restrict__ C, int cmode,         // 0: full [8192][256]; 1: compact rows m%256==0
    const float* __restrict__ Wsn, const float* __restrict__ Whn,
    float* __restrict__ s_out, float* __restrict__ h_out)
{
    __shared__ __align__(16) char smem[49152];
    ushort* Ahi = (ushort*)smem;            // 64*64
    ushort* Alo = Ahi + 4096;
    ushort* Bhi = (ushort*)(smem + 16384);  // 128*64
    ushort* Blo = Bhi + 8192;
    float*  CT  = (float*)(smem + 16384);   // 64*128 fp32, overlays B bufs
    float*  part = (float*)smem;            // 64*8*5 fp32, overlays A bufs

    const int tid = threadIdx.x;
    const int lane = tid & 63, wid = tid >> 6;
    const int wm = wid >> 2, wn = wid & 3;
    const int m0 = blockIdx.x * 64, n0 = blockIdx.y * 128;

    f32x4 acc[2][2];
#pragma unroll
    for (int mi = 0; mi < 2; ++mi)
#pragma unroll
        for (int ni = 0; ni < 2; ++ni)
            acc[mi][ni] = (f32x4){0.f, 0.f, 0.f, 0.f};

    for (int k0 = 0; k0 < K; k0 += 64) {
        __syncthreads();
#pragma unroll
        for (int i = 0; i < 2; ++i) {       // stage A 64x64 fp32 -> hi/lo, swizzled
            int lin = tid + i * 512;
            int row = lin >> 4, c4 = (lin & 15) * 4;
            float4 v = *reinterpret_cast<const float4*>(&A[(size_t)(m0 + row) * K + k0 + c4]);
            int idx = (row * 64 + c4) ^ ((row & 7) << 3);
            ushort4 hi, lo;
            hi.x = f2bf(v.x); lo.x = f2bf(v.x - bf2f(hi.x));
            hi.y = f2bf(v.y); lo.y = f2bf(v.y - bf2f(hi.y));
            hi.z = f2bf(v.z); lo.z = f2bf(v.z - bf2f(hi.z));
            hi.w = f2bf(v.w); lo.w = f2bf(v.w - bf2f(hi.w));
            *reinterpret_cast<ushort4*>(&Ahi[idx]) = hi;
            *reinterpret_cast<ushort4*>(&Alo[idx]) = lo;
        }
#pragma unroll
        for (int i = 0; i < 2; ++i) {       // stage B 128x64 pre-split copy, swizzled
            int lin = tid + i * 512;
            int row = lin >> 3, c8 = (lin & 7) * 8;
            int idx = (row * 64 + c8) ^ ((row & 7) << 3);
            size_t g = (size_t)(n0 + row) * K + k0 + c8;
            *reinterpret_cast<float4*>(&Bhi[idx]) = *reinterpret_cast<const float4*>(&Wthi[g]);
            *reinterpret_cast<float4*>(&Blo[idx]) = *reinterpret_cast<const float4*>(&Wtlo[g]);
        }
        __syncthreads();
#pragma unroll
        for (int kc = 0; kc < 64; kc += 32) {
            int kofs = kc + (lane >> 4) * 8;
            bf16x8 ah[2], al[2], bh[2], bl[2];
#pragma unroll
            for (int mi = 0; mi < 2; ++mi) {
                int r = wm * 32 + mi * 16 + (lane & 15);
                int idx = (r * 64 + kofs) ^ ((r & 7) << 3);
                ah[mi] = *reinterpret_cast<const bf16x8*>(&Ahi[idx]);
                al[mi] = *reinterpret_cast<const bf16x8*>(&Alo[idx]);
            }
#pragma unroll
            for (int ni = 0; ni < 2; ++ni) {
                int r = wn * 32 + ni * 16 + (lane & 15);
                int idx = (r * 64 + kofs) ^ ((r & 7) << 3);
                bh[ni] = *reinterpret_cast<const bf16x8*>(&Bhi[idx]);
                bl[ni] = *reinterpret_cast<const bf16x8*>(&Blo[idx]);
            }
#pragma unroll
            for (int mi = 0; mi < 2; ++mi)
#pragma unroll
                for (int ni = 0; ni < 2; ++ni) {
                    acc[mi][ni] = __builtin_amdgcn_mfma_f32_16x16x32_bf16(ah[mi], bh[ni], acc[mi][ni], 0, 0, 0);
                    acc[mi][ni] = __builtin_amdgcn_mfma_f32_16x16x32_bf16(ah[mi], bl[ni], acc[mi][ni], 0, 0, 0);
                    acc[mi][ni] = __builtin_amdgcn_mfma_f32_16x16x32_bf16(al[mi], bh[ni], acc[mi][ni], 0, 0, 0);
                }
        }
    }
    __syncthreads();   // all B reads done -> CT may overwrite

    // epilogue: + agg@Wa + bias, leaky, park in CT (and global C per cmode)
#pragma unroll
    for (int ni = 0; ni < 2; ++ni) {
        int nl = wn * 32 + ni * 16 + (lane & 15);   // local col 0..127
        int n = n0 + nl;
        float w0 = Wfull[n], w1 = Wfull[256 + n], bz = bias[n];
#pragma unroll
        for (int mi = 0; mi < 2; ++mi) {
            int mb = wm * 32 + mi * 16 + ((lane >> 4) << 2);  // local row
#pragma unroll
            for (int r = 0; r < 4; ++r) {
                int ml = mb + r, m = m0 + ml;
                float v = acc[mi][ni][r] + fmaf(agg[m * 2 + 0], w0, fmaf(agg[m * 2 + 1], w1, bz));
                v = v >= 0.f ? v : 0.01f * v;      // both fused layers are leaky
                CT[ml * 128 + nl] = v;
                if (cmode == 0) C[(size_t)m * 256 + n] = v;
                else if ((m & 255) == 0) C[(m >> 8) * 256 + n] = v;
            }
        }
    }
    __syncthreads();

    // phase2: per-row dot with Wsn/Whn over this block's 128 cols
    {
        int row = tid >> 3, sub = tid & 7;
        float p0 = 0.f, p1 = 0.f, p2 = 0.f, p3 = 0.f, p4 = 0.f;
#pragma unroll
        for (int i = 0; i < 16; ++i) {
            int c = sub * 16 + i;
            float v = CT[row * 128 + c];
            int n = n0 + c;
            p0 = fmaf(v, Wsn[n * 3 + 0], p0);
            p1 = fmaf(v, Wsn[n * 3 + 1], p1);
            p2 = fmaf(v, Wsn[n * 3 + 2], p2);
            p3 = fmaf(v, Whn[n * 2 + 0], p3);
            p4 = fmaf(v, Whn[n * 2 + 1], p4);
        }
        float* pp = &part[(row * 8 + sub) * 5];
        pp[0] = p0; pp[1] = p1; pp[2] = p2; pp[3] = p3; pp[4] = p4;
    }
    __syncthreads();
    if (tid < 320) {
        int row = tid / 5, o = tid - row * 5;
        float sum = 0.f;
#pragma unroll
        for (int k = 0; k < 8; ++k) sum += part[(row * 8 + k) * 5 + o];
        if (o < 3) atomicAdd(&s_out[(m0 + row) * 3 + o], sum);
        else       atomicAdd(&h_out[(m0 + row) * 2 + (o - 3)], sum);
    }
}

// ---------------- K6: per-graph kNN of row g*256 + final matvec ----------------
__global__ __launch_bounds__(256) void knn3_final(
    const float* __restrict__ s, const float* __restrict__ h,
    const float* __restrict__ h2c,   // [32][256] leaky'd layer-2 rows g*256
    const float* __restrict__ Wo, const float* __restrict__ bo,
    float* __restrict__ out)
{
    __shared__ float aggL[2];
    __shared__ float pm[8][32];
    int g = blockIdx.x, tid = threadIdx.x;
    if (tid < 64) {
        float a0, a1;
        knn_row_agg(s, h, g * GN, g * GN, tid, a0, a1);
        if (tid == 0) { aggL[0] = a0; aggL[1] = a1; }
    }
    __syncthreads();
    int o = tid & 31, seg = tid >> 5;
    const float* xr = h2c + g * 256;
    float p = 0.f;
#pragma unroll
    for (int i = 0; i < 32; ++i) {
        int c = seg * 32 + i;
        p = fmaf(xr[c], Wo[(2 + c) * 32 + o], p);
    }
    pm[seg][o] = p;
    __syncthreads();
    if (tid < 32) {
        float acc = fmaf(aggL[0], Wo[o], fmaf(aggL[1], Wo[32 + o], bo[o]));
#pragma unroll
        for (int k = 0; k < 8; ++k) acc += pm[k][o];
        out[g * 32 + o] = acc;
    }
}

extern "C" void kernel_launch(void* const* d_in, const int* in_sizes, int n_in,
                              void* d_out, int out_size, void* d_ws, size_t ws_size,
                              hipStream_t stream) {
    const float* X   = (const float*)d_in[0];
    const float* Ws1 = (const float*)d_in[2];  const float* bs1 = (const float*)d_in[3];
    const float* Wh1 = (const float*)d_in[4];  const float* bh1 = (const float*)d_in[5];
    const float* Wo1 = (const float*)d_in[6];  const float* bo1 = (const float*)d_in[7];
    const float* Ws2 = (const float*)d_in[8];  const float* bs2 = (const float*)d_in[9];
    const float* Wh2 = (const float*)d_in[10]; const float* bh2 = (const float*)d_in[11];
    const float* Wo2 = (const float*)d_in[12]; const float* bo2 = (const float*)d_in[13];
    const float* Ws3 = (const float*)d_in[14]; const float* bs3 = (const float*)d_in[15];
    const float* Wh3 = (const float*)d_in[16]; const float* bh3 = (const float*)d_in[17];
    const float* Wo3 = (const float*)d_in[18]; const float* bo3 = (const float*)d_in[19];

    float* p = (float*)d_ws;
    float* h1   = p; p += (size_t)NTOT * 256;   // 2,097,152
    float* h2c  = p; p += 32 * 256;
    float* s1   = p; p += NTOT * 3;
    float* hp1  = p; p += NTOT * 2;
    float* s2   = p; p += NTOT * 3;
    float* hp2  = p; p += NTOT * 2;
    float* s3   = p; p += NTOT * 3;
    float* hp3  = p; p += NTOT * 2;
    float* aggb = p; p += NTOT * 2;
    ushort* Wt1hi = (ushort*)p;
    ushort* Wt1lo = Wt1hi + 256 * 64;
    ushort* Wt2hi = Wt1lo + 256 * 64;
    ushort* Wt2lo = Wt2hi + 256 * 256;

    k_front<<<2688, 256, 0, stream>>>(X, Ws1, bs1, Wh1, bh1, Wo1, Wo2,
                                      bs2, bh2, bs3, bh3,
                                      Wt1hi, Wt1lo, Wt2hi, Wt2lo,
                                      s1, hp1, s2, hp2, s3, hp3);
    knn_kernel<<<2048, 256, 0, stream>>>(s1, hp1, aggb);
    gemm_fused<<<dim3(NTOT / 64, 2), 512, 0, stream>>>(X, 64, Wt1hi, Wt1lo, Wo1, bo1, aggb,
                                                       h1, 0, Ws2, Wh2, s2, hp2);
    knn_kernel<<<2048, 256, 0, stream>>>(s2, hp2, aggb);
    gemm_fused<<<dim3(NTOT / 64, 2), 512, 0, stream>>>(h1, 256, Wt2hi, Wt2lo, Wo2, bo2, aggb,
                                                       h2c, 1, Ws3, Wh3, s3, hp3);
    knn3_final<<<NGRAPH, 256, 0, stream>>>(s3, hp3, h2c, Wo3, bo3, (float*)d_out);
}

// Round 4
// 86.229 us; speedup vs baseline: 1.5881x; 1.1922x over previous
//
#include <hip/hip_runtime.h>
#include <hip/hip_bf16.h>

// GravNet: 32 graphs x 256 nodes, IN=64, HID=256, OUT=32, K=20, SPACE=3, PROP=2
// 6-launch pipeline:
//  K1 k_front   : sh1 | weight split/transpose | bias-init s/h bufs | X hi/lo split
//  K2 knn       : layer-1 kNN+aggregate (u32-bit butterfly, ballot winner, reg-h)
//  K3 gemm<64,0>: h1(split bf16 planes) = leaky([agg,X]@Wo1+bo1) + fused s2/h2 partials
//  K4 knn       : layer-2
//  K5 gemm<256,1>: h2 compact rows g*256 + fused s3/h3 partials
//  K6 knn3_final: per-graph kNN of row g*256 + final 258->32 matvec
// GEMM x-part: split-bf16 MFMA (hi/lo, 3 products) == fp32 precision; operands pre-split
// in global, fragments loaded straight to VGPRs (no LDS staging, no k-loop barriers).

#define NGRAPH 32
#define GN 256
#define NTOT (NGRAPH*GN) // 8192
#define KNN 20

typedef __attribute__((ext_vector_type(8))) short bf16x8;
typedef __attribute__((ext_vector_type(4))) float f32x4;

__device__ __forceinline__ ushort f2bf(float x) {
    union { float f; unsigned u; } a; a.f = x;
    unsigned r = a.u + 0x7FFFu + ((a.u >> 16) & 1u);   // RNE
    return (ushort)(r >> 16);
}
__device__ __forceinline__ float bf2f(ushort h) {
    union { unsigned u; float f; } b; b.u = ((unsigned)h) << 16;
    return b.f;
}
__device__ __forceinline__ bf16x8 ld8(const ushort* p) {
    return *reinterpret_cast<const bf16x8*>(p);
}

// ---------------- K1: sh1 | prep | init | Xsplit (grid-split) ----------------
__global__ __launch_bounds__(256) void k_front(
    const float* __restrict__ X,
    const float* __restrict__ Ws1, const float* __restrict__ bs1,
    const float* __restrict__ Wh1, const float* __restrict__ bh1,
    const float* __restrict__ Wo1, const float* __restrict__ Wo2,
    const float* __restrict__ bs2, const float* __restrict__ bh2,
    const float* __restrict__ bs3, const float* __restrict__ bh3,
    ushort* __restrict__ Wt1hi, ushort* __restrict__ Wt1lo,
    ushort* __restrict__ Wt2hi, ushort* __restrict__ Wt2lo,
    ushort* __restrict__ Xhi, ushort* __restrict__ Xlo,
    float* __restrict__ s1, float* __restrict__ h1p,
    float* __restrict__ s2, float* __restrict__ h2p,
    float* __restrict__ s3, float* __restrict__ h3p)
{
    int b = blockIdx.x, tid = threadIdx.x;
    if (b < 2048) {                       // ---- sh1: 4 rows/block, cin=64
        int gw = b * 4 + (tid >> 6);
        int lane = tid & 63;
        float xv = X[(size_t)gw * 64 + lane];
        float a0 = xv * Ws1[lane * 3 + 0];
        float a1 = xv * Ws1[lane * 3 + 1];
        float a2 = xv * Ws1[lane * 3 + 2];
        float a3 = xv * Wh1[lane * 2 + 0];
        float a4 = xv * Wh1[lane * 2 + 1];
#pragma unroll
        for (int m = 1; m < 64; m <<= 1) {
            a0 += __shfl_xor(a0, m); a1 += __shfl_xor(a1, m); a2 += __shfl_xor(a2, m);
            a3 += __shfl_xor(a3, m); a4 += __shfl_xor(a4, m);
        }
        if (lane == 0) {
            s1[gw * 3 + 0] = a0 + bs1[0];
            s1[gw * 3 + 1] = a1 + bs1[1];
            s1[gw * 3 + 2] = a2 + bs1[2];
            h1p[gw * 2 + 0] = a3 + bh1[0];
            h1p[gw * 2 + 1] = a4 + bh1[1];
        }
    } else if (b < 2368) {                // ---- prep: Wo[2+c][n] -> Wt[n][c] hi/lo
        int t = (b - 2048) * 256 + tid;
        if (t < 65536) {
            int n = t >> 8, c = t & 255;
            float v = Wo2[(size_t)(2 + c) * 256 + n];
            ushort hi = f2bf(v);
            Wt2hi[n * 256 + c] = hi;
            Wt2lo[n * 256 + c] = f2bf(v - bf2f(hi));
        } else {
            int u = t - 65536;
            int n = u >> 6, c = u & 63;
            float v = Wo1[(size_t)(2 + c) * 256 + n];
            ushort hi = f2bf(v);
            Wt1hi[n * 64 + c] = hi;
            Wt1lo[n * 64 + c] = f2bf(v - bf2f(hi));
        }
    } else if (b < 2688) {                // ---- init s2/h2/s3/h3 with biases
        int u = (b - 2368) * 256 + tid;   // 0..81919
        if (u < 24576)      s2[u] = bs2[u % 3];
        else if (u < 40960) { int w = u - 24576; h2p[w] = bh2[w & 1]; }
        else if (u < 65536) { int w = u - 40960; s3[w] = bs3[w % 3]; }
        else                { int w = u - 65536; h3p[w] = bh3[w & 1]; }
    } else {                              // ---- X hi/lo split: 2 floats/thread
        int t = (b - 2688) * 256 + tid;   // 0..262143
        float2 v = *reinterpret_cast<const float2*>(&X[(size_t)t * 2]);
        ushort hx = f2bf(v.x), hy = f2bf(v.y);
        Xhi[t * 2 + 0] = hx; Xlo[t * 2 + 0] = f2bf(v.x - bf2f(hx));
        Xhi[t * 2 + 1] = hy; Xlo[t * 2 + 1] = f2bf(v.y - bf2f(hy));
    }
}

// ---------------- kNN + weighted aggregation core (one wave per row) ----------------
// d2 >= 0 so u32 bit-order == float order. Butterfly min on u32; winner = lowest lane
// holding the min (idx tie-break within lane exact; cross-lane exact-bit d2 ties are
// measure-zero). h prefetched to registers -> winner update is pure VALU.
// Early exit when min d2 > 2.0 (residual weights < 2e-9).
__device__ __forceinline__ void knn_row_agg(
    const float* __restrict__ s, const float* __restrict__ h,
    int base, int row, int lane, float& out0, float& out1)
{
    float s0 = s[row * 3 + 0], s1 = s[row * 3 + 1], s2 = s[row * 3 + 2];
    float s2row = s0 * s0 + s1 * s1 + s2 * s2;
    auto calc = [&](int j) {
        const float* sj = s + (size_t)(base + j) * 3;
        float t0 = sj[0], t1 = sj[1], t2 = sj[2];
        float s2j = t0 * t0 + t1 * t1 + t2 * t2;
        float dot = s0 * t0 + s1 * t1 + s2 * t2;
        float d2 = s2row + s2j - 2.0f * dot;
        return __float_as_uint(d2 > 0.f ? d2 : 0.f);
    };
    unsigned ua = calc(lane),       ub = calc(lane + 64);
    unsigned uc = calc(lane + 128), ud = calc(lane + 192);
    float2 hA = *reinterpret_cast<const float2*>(&h[(size_t)(base + lane) * 2]);
    float2 hB = *reinterpret_cast<const float2*>(&h[(size_t)(base + lane + 64) * 2]);
    float2 hC = *reinterpret_cast<const float2*>(&h[(size_t)(base + lane + 128) * 2]);
    float2 hD = *reinterpret_cast<const float2*>(&h[(size_t)(base + lane + 192) * 2]);

    float acc0 = 0.f, acc1 = 0.f;
#pragma unroll 1
    for (int it = 0; it < KNN; ++it) {
        // local min over 4 slots (idx-ordered, strict <) carrying h
        unsigned bv = ua; float bh0 = hA.x, bh1 = hA.y;
        if (ub < bv) { bv = ub; bh0 = hB.x; bh1 = hB.y; }
        if (uc < bv) { bv = uc; bh0 = hC.x; bh1 = hC.y; }
        if (ud < bv) { bv = ud; bh0 = hD.x; bh1 = hD.y; }
        unsigned gv = bv;
#pragma unroll
        for (int m = 1; m < 64; m <<= 1) {
            unsigned o = __shfl_xor(gv, m);
            gv = o < gv ? o : gv;
        }
        float d2 = __uint_as_float(gv);
        if (d2 > 2.0f) break;                    // wave-uniform
        unsigned long long mask = __ballot(bv == gv);
        int wl = __ffsll(mask) - 1;
        if (lane == wl) {
            float w = __expf(-10.0f * d2);
            acc0 = fmaf(w, bh0, acc0);
            acc1 = fmaf(w, bh1, acc1);
            ua = (ua == gv) ? 0xFFFFFFFFu : ua;
            ub = (ub == gv) ? 0xFFFFFFFFu : ub;
            uc = (uc == gv) ? 0xFFFFFFFFu : uc;
            ud = (ud == gv) ? 0xFFFFFFFFu : ud;
        }
    }
#pragma unroll
    for (int m = 1; m < 64; m <<= 1) {
        acc0 += __shfl_xor(acc0, m);
        acc1 += __shfl_xor(acc1, m);
    }
    out0 = acc0; out1 = acc1;
}

__global__ __launch_bounds__(256) void knn_kernel(
    const float* __restrict__ s, const float* __restrict__ h,
    float* __restrict__ agg)
{
    int gw = (int)(blockIdx.x * 4 + (threadIdx.x >> 6));
    int lane = threadIdx.x & 63;
    float a0, a1;
    knn_row_agg(s, h, gw & ~(GN - 1), gw, lane, a0, a1);
    if (lane == 0) {
        agg[gw * 2 + 0] = a0;
        agg[gw * 2 + 1] = a1;
    }
}

// ---------------- MFMA split-bf16 GEMM (no LDS staging) + fused s/h projection ----------
// Operands pre-split bf16 hi/lo planes [rows][K]; fragments loaded 16B direct from global.
// CMODE 0: write C split into Chi/Clo planes [8192][256]; CMODE 1: compact fp32 rows m%256==0.
// Block 512 thr (8 waves, 2m x 4n), BM=64, BN=128. Grid (128, 2).
template<int K, int CMODE>
__global__ __launch_bounds__(512) void gemm_fused(
    const ushort* __restrict__ Ahi, const ushort* __restrict__ Alo,
    const ushort* __restrict__ Bhi, const ushort* __restrict__ Blo,
    const float* __restrict__ Wfull, const float* __restrict__ bias,
    const float* __restrict__ agg,
    float* __restrict__ Cf, ushort* __restrict__ Chi, ushort* __restrict__ Clo,
    const float* __restrict__ Wsn, const float* __restrict__ Whn,
    float* __restrict__ s_out, float* __restrict__ h_out)
{
    __shared__ float CT[64 * 128];
    __shared__ float part[64 * 8 * 5];

    const int tid = threadIdx.x;
    const int lane = tid & 63, wid = tid >> 6;
    const int wm = wid >> 2, wn = wid & 3;
    const int m0 = blockIdx.x * 64, n0 = blockIdx.y * 128;

    f32x4 acc[2][2];
#pragma unroll
    for (int mi = 0; mi < 2; ++mi)
#pragma unroll
        for (int ni = 0; ni < 2; ++ni)
            acc[mi][ni] = (f32x4){0.f, 0.f, 0.f, 0.f};

#pragma unroll
    for (int kof = 0; kof < K; kof += 32) {
        int kch = kof + (lane >> 4) * 8;
        bf16x8 ah[2], al[2], bh[2], bl[2];
#pragma unroll
        for (int mi = 0; mi < 2; ++mi) {
            size_t off = (size_t)(m0 + wm * 32 + mi * 16 + (lane & 15)) * K + kch;
            ah[mi] = ld8(Ahi + off); al[mi] = ld8(Alo + off);
        }
#pragma unroll
        for (int ni = 0; ni < 2; ++ni) {
            size_t off = (size_t)(n0 + wn * 32 + ni * 16 + (lane & 15)) * K + kch;
            bh[ni] = ld8(Bhi + off); bl[ni] = ld8(Blo + off);
        }
#pragma unroll
        for (int mi = 0; mi < 2; ++mi)
#pragma unroll
            for (int ni = 0; ni < 2; ++ni) {
                acc[mi][ni] = __builtin_amdgcn_mfma_f32_16x16x32_bf16(ah[mi], bh[ni], acc[mi][ni], 0, 0, 0);
                acc[mi][ni] = __builtin_amdgcn_mfma_f32_16x16x32_bf16(ah[mi], bl[ni], acc[mi][ni], 0, 0, 0);
                acc[mi][ni] = __builtin_amdgcn_mfma_f32_16x16x32_bf16(al[mi], bh[ni], acc[mi][ni], 0, 0, 0);
            }
    }

    // epilogue: + agg@Wa + bias, leaky, park in CT + global writes
    // C/D map: col=lane&15, row=(lane>>4)*4+reg (m89-verified)
#pragma unroll
    for (int ni = 0; ni < 2; ++ni) {
        int nl = wn * 32 + ni * 16 + (lane & 15);
        int n = n0 + nl;
        float w0 = Wfull[n], w1 = Wfull[256 + n], bz = bias[n];
#pragma unroll
        for (int mi = 0; mi < 2; ++mi) {
            int mb = wm * 32 + mi * 16 + ((lane >> 4) << 2);
#pragma unroll
            for (int r = 0; r < 4; ++r) {
                int ml = mb + r, m = m0 + ml;
                float v = acc[mi][ni][r] + fmaf(agg[m * 2 + 0], w0, fmaf(agg[m * 2 + 1], w1, bz));
                v = v >= 0.f ? v : 0.01f * v;
                CT[ml * 128 + nl] = v;
                if (CMODE == 0) {
                    ushort hv = f2bf(v);
                    Chi[(size_t)m * 256 + n] = hv;
                    Clo[(size_t)m * 256 + n] = f2bf(v - bf2f(hv));
                } else if ((m & 255) == 0) {
                    Cf[(m >> 8) * 256 + n] = v;
                }
            }
        }
    }
    __syncthreads();

    // phase2: per-row dot with Wsn/Whn over this block's 128 cols
    {
        int row = tid >> 3, sub = tid & 7;
        float p0 = 0.f, p1 = 0.f, p2 = 0.f, p3 = 0.f, p4 = 0.f;
#pragma unroll
        for (int i = 0; i < 16; ++i) {
            int c = sub * 16 + i;
            float v = CT[row * 128 + c];
            int n = n0 + c;
            p0 = fmaf(v, Wsn[n * 3 + 0], p0);
            p1 = fmaf(v, Wsn[n * 3 + 1], p1);
            p2 = fmaf(v, Wsn[n * 3 + 2], p2);
            p3 = fmaf(v, Whn[n * 2 + 0], p3);
            p4 = fmaf(v, Whn[n * 2 + 1], p4);
        }
        float* pp = &part[(row * 8 + sub) * 5];
        pp[0] = p0; pp[1] = p1; pp[2] = p2; pp[3] = p3; pp[4] = p4;
    }
    __syncthreads();
    if (tid < 320) {
        int row = tid / 5, o = tid - row * 5;
        float sum = 0.f;
#pragma unroll
        for (int k = 0; k < 8; ++k) sum += part[(row * 8 + k) * 5 + o];
        if (o < 3) atomicAdd(&s_out[(m0 + row) * 3 + o], sum);
        else       atomicAdd(&h_out[(m0 + row) * 2 + (o - 3)], sum);
    }
}

// ---------------- K6: per-graph kNN of row g*256 + final matvec ----------------
__global__ __launch_bounds__(256) void knn3_final(
    const float* __restrict__ s, const float* __restrict__ h,
    const float* __restrict__ h2c,   // [32][256] leaky'd layer-2 rows g*256
    const float* __restrict__ Wo, const float* __restrict__ bo,
    float* __restrict__ out)
{
    __shared__ float aggL[2];
    __shared__ float pm[8][32];
    int g = blockIdx.x, tid = threadIdx.x;
    if (tid < 64) {
        float a0, a1;
        knn_row_agg(s, h, g * GN, g * GN, tid, a0, a1);
        if (tid == 0) { aggL[0] = a0; aggL[1] = a1; }
    }
    __syncthreads();
    int o = tid & 31, seg = tid >> 5;
    const float* xr = h2c + g * 256;
    float p = 0.f;
#pragma unroll
    for (int i = 0; i < 32; ++i) {
        int c = seg * 32 + i;
        p = fmaf(xr[c], Wo[(2 + c) * 32 + o], p);
    }
    pm[seg][o] = p;
    __syncthreads();
    if (tid < 32) {
        float acc = fmaf(aggL[0], Wo[o], fmaf(aggL[1], Wo[32 + o], bo[o]));
#pragma unroll
        for (int k = 0; k < 8; ++k) acc += pm[k][o];
        out[g * 32 + o] = acc;
    }
}

extern "C" void kernel_launch(void* const* d_in, const int* in_sizes, int n_in,
                              void* d_out, int out_size, void* d_ws, size_t ws_size,
                              hipStream_t stream) {
    const float* X   = (const float*)d_in[0];
    const float* Ws1 = (const float*)d_in[2];  const float* bs1 = (const float*)d_in[3];
    const float* Wh1 = (const float*)d_in[4];  const float* bh1 = (const float*)d_in[5];
    const float* Wo1 = (const float*)d_in[6];  const float* bo1 = (const float*)d_in[7];
    const float* Ws2 = (const float*)d_in[8];  const float* bs2 = (const float*)d_in[9];
    const float* Wh2 = (const float*)d_in[10]; const float* bh2 = (const float*)d_in[11];
    const float* Wo2 = (const float*)d_in[12]; const float* bo2 = (const float*)d_in[13];
    const float* Ws3 = (const float*)d_in[14]; const float* bs3 = (const float*)d_in[15];
    const float* Wh3 = (const float*)d_in[16]; const float* bh3 = (const float*)d_in[17];
    const float* Wo3 = (const float*)d_in[18]; const float* bo3 = (const float*)d_in[19];

    float* p = (float*)d_ws;
    float* s1   = p; p += NTOT * 3;
    float* hp1  = p; p += NTOT * 2;
    float* s2   = p; p += NTOT * 3;
    float* hp2  = p; p += NTOT * 2;
    float* s3   = p; p += NTOT * 3;
    float* hp3  = p; p += NTOT * 2;
    float* aggb = p; p += NTOT * 2;
    float* h2c  = p; p += 32 * 256;
    ushort* q = (ushort*)p;
    ushort* Xhi  = q; q += (size_t)NTOT * 64;
    ushort* Xlo  = q; q += (size_t)NTOT * 64;
    ushort* h1hi = q; q += (size_t)NTOT * 256;
    ushort* h1lo = q; q += (size_t)NTOT * 256;
    ushort* Wt1hi = q; q += 256 * 64;
    ushort* Wt1lo = q; q += 256 * 64;
    ushort* Wt2hi = q; q += 256 * 256;
    ushort* Wt2lo = q; q += 256 * 256;

    k_front<<<3712, 256, 0, stream>>>(X, Ws1, bs1, Wh1, bh1, Wo1, Wo2,
                                      bs2, bh2, bs3, bh3,
                                      Wt1hi, Wt1lo, Wt2hi, Wt2lo, Xhi, Xlo,
                                      s1, hp1, s2, hp2, s3, hp3);
    knn_kernel<<<2048, 256, 0, stream>>>(s1, hp1, aggb);
    gemm_fused<64, 0><<<dim3(128, 2), 512, 0, stream>>>(Xhi, Xlo, Wt1hi, Wt1lo,
                                                        Wo1, bo1, aggb,
                                                        nullptr, h1hi, h1lo,
                                                        Ws2, Wh2, s2, hp2);
    knn_kernel<<<2048, 256, 0, stream>>>(s2, hp2, aggb);
    gemm_fused<256, 1><<<dim3(128, 2), 512, 0, stream>>>(h1hi, h1lo, Wt2hi, Wt2lo,
                                                         Wo2, bo2, aggb,
                                                         h2c, nullptr, nullptr,
                                                         Ws3, Wh3, s3, hp3);
    knn3_final<<<NGRAPH, 256, 0, stream>>>(s3, hp3, h2c, Wo3, bo3, (float*)d_out);
}

// Round 5
// 79.986 us; speedup vs baseline: 1.7120x; 1.0780x over previous
//
#include <hip/hip_runtime.h>
#include <hip/hip_bf16.h>

// GravNet: 32 graphs x 256 nodes, IN=64, HID=256, OUT=32, K=20, SPACE=3, PROP=2
// 6-launch pipeline:
//  K1 k_front   : sh1 | weight split/transpose | bias-init s/h bufs | X hi/lo split
//  K2 knn       : layer-1 kNN+aggregate (u32-bit butterfly, ballot winner, reg-h)
//  K3 gemm<64,0>: h1(split bf16 planes) = leaky([agg,X]@Wo1+bo1) + fused s2/h2 partials
//  K4 knn       : layer-2
//  K5 gemm<256,1>: h2 compact rows g*256 + fused s3/h3 partials
//  K6 knn3_final: per-graph kNN of row g*256 + final 258->32 matvec
// GEMM x-part: split-bf16 MFMA (hi/lo, 3 products) == fp32 precision; operands pre-split
// in global, fragments loaded straight to VGPRs (no LDS staging; k-loop unroll capped to
// bound the load window / VGPRs). C written coalesced from the CT LDS tile (stride 129).

#define NGRAPH 32
#define GN 256
#define NTOT (NGRAPH*GN) // 8192
#define KNN 20
#define CTS 129          // CT leading dim (floats) — breaks LDS bank aliasing

typedef __attribute__((ext_vector_type(8))) short bf16x8;
typedef __attribute__((ext_vector_type(4))) float f32x4;

__device__ __forceinline__ ushort f2bf(float x) {
    union { float f; unsigned u; } a; a.f = x;
    unsigned r = a.u + 0x7FFFu + ((a.u >> 16) & 1u);   // RNE
    return (ushort)(r >> 16);
}
__device__ __forceinline__ float bf2f(ushort h) {
    union { unsigned u; float f; } b; b.u = ((unsigned)h) << 16;
    return b.f;
}
__device__ __forceinline__ bf16x8 ld8(const ushort* p) {
    return *reinterpret_cast<const bf16x8*>(p);
}
__device__ __forceinline__ unsigned pack2(ushort a, ushort b) {
    return (unsigned)a | ((unsigned)b << 16);
}

// ---------------- K1: sh1 | prep | init | Xsplit (grid-split) ----------------
__global__ __launch_bounds__(256) void k_front(
    const float* __restrict__ X,
    const float* __restrict__ Ws1, const float* __restrict__ bs1,
    const float* __restrict__ Wh1, const float* __restrict__ bh1,
    const float* __restrict__ Wo1, const float* __restrict__ Wo2,
    const float* __restrict__ bs2, const float* __restrict__ bh2,
    const float* __restrict__ bs3, const float* __restrict__ bh3,
    ushort* __restrict__ Wt1hi, ushort* __restrict__ Wt1lo,
    ushort* __restrict__ Wt2hi, ushort* __restrict__ Wt2lo,
    ushort* __restrict__ Xhi, ushort* __restrict__ Xlo,
    float* __restrict__ s1, float* __restrict__ h1p,
    float* __restrict__ s2, float* __restrict__ h2p,
    float* __restrict__ s3, float* __restrict__ h3p)
{
    int b = blockIdx.x, tid = threadIdx.x;
    if (b < 2048) {                       // ---- sh1: 4 rows/block, cin=64
        int gw = b * 4 + (tid >> 6);
        int lane = tid & 63;
        float xv = X[(size_t)gw * 64 + lane];
        float a0 = xv * Ws1[lane * 3 + 0];
        float a1 = xv * Ws1[lane * 3 + 1];
        float a2 = xv * Ws1[lane * 3 + 2];
        float a3 = xv * Wh1[lane * 2 + 0];
        float a4 = xv * Wh1[lane * 2 + 1];
#pragma unroll
        for (int m = 1; m < 64; m <<= 1) {
            a0 += __shfl_xor(a0, m); a1 += __shfl_xor(a1, m); a2 += __shfl_xor(a2, m);
            a3 += __shfl_xor(a3, m); a4 += __shfl_xor(a4, m);
        }
        if (lane == 0) {
            s1[gw * 3 + 0] = a0 + bs1[0];
            s1[gw * 3 + 1] = a1 + bs1[1];
            s1[gw * 3 + 2] = a2 + bs1[2];
            h1p[gw * 2 + 0] = a3 + bh1[0];
            h1p[gw * 2 + 1] = a4 + bh1[1];
        }
    } else if (b < 2368) {                // ---- prep: Wo[2+c][n] -> Wt[n][c] hi/lo
        int t = (b - 2048) * 256 + tid;
        if (t < 65536) {
            int n = t >> 8, c = t & 255;
            float v = Wo2[(size_t)(2 + c) * 256 + n];
            ushort hi = f2bf(v);
            Wt2hi[n * 256 + c] = hi;
            Wt2lo[n * 256 + c] = f2bf(v - bf2f(hi));
        } else {
            int u = t - 65536;
            int n = u >> 6, c = u & 63;
            float v = Wo1[(size_t)(2 + c) * 256 + n];
            ushort hi = f2bf(v);
            Wt1hi[n * 64 + c] = hi;
            Wt1lo[n * 64 + c] = f2bf(v - bf2f(hi));
        }
    } else if (b < 2688) {                // ---- init s2/h2/s3/h3 with biases
        int u = (b - 2368) * 256 + tid;   // 0..81919
        if (u < 24576)      s2[u] = bs2[u % 3];
        else if (u < 40960) { int w = u - 24576; h2p[w] = bh2[w & 1]; }
        else if (u < 65536) { int w = u - 40960; s3[w] = bs3[w % 3]; }
        else                { int w = u - 65536; h3p[w] = bh3[w & 1]; }
    } else {                              // ---- X hi/lo split: 2 floats/thread
        int t = (b - 2688) * 256 + tid;   // 0..262143
        float2 v = *reinterpret_cast<const float2*>(&X[(size_t)t * 2]);
        ushort hx = f2bf(v.x), hy = f2bf(v.y);
        Xhi[t * 2 + 0] = hx; Xlo[t * 2 + 0] = f2bf(v.x - bf2f(hx));
        Xhi[t * 2 + 1] = hy; Xlo[t * 2 + 1] = f2bf(v.y - bf2f(hy));
    }
}

// ---------------- kNN + weighted aggregation core (one wave per row) ----------------
// d2 >= 0 so u32 bit-order == float order. Butterfly min on u32; winner = lowest lane
// holding the min. h prefetched to registers -> winner update is pure VALU.
// Early exit when min d2 > 2.0 (residual weights < 2e-9).
__device__ __forceinline__ void knn_row_agg(
    const float* __restrict__ s, const float* __restrict__ h,
    int base, int row, int lane, float& out0, float& out1)
{
    float s0 = s[row * 3 + 0], s1 = s[row * 3 + 1], s2 = s[row * 3 + 2];
    float s2row = s0 * s0 + s1 * s1 + s2 * s2;
    auto calc = [&](int j) {
        const float* sj = s + (size_t)(base + j) * 3;
        float t0 = sj[0], t1 = sj[1], t2 = sj[2];
        float s2j = t0 * t0 + t1 * t1 + t2 * t2;
        float dot = s0 * t0 + s1 * t1 + s2 * t2;
        float d2 = s2row + s2j - 2.0f * dot;
        return __float_as_uint(d2 > 0.f ? d2 : 0.f);
    };
    unsigned ua = calc(lane),       ub = calc(lane + 64);
    unsigned uc = calc(lane + 128), ud = calc(lane + 192);
    float2 hA = *reinterpret_cast<const float2*>(&h[(size_t)(base + lane) * 2]);
    float2 hB = *reinterpret_cast<const float2*>(&h[(size_t)(base + lane + 64) * 2]);
    float2 hC = *reinterpret_cast<const float2*>(&h[(size_t)(base + lane + 128) * 2]);
    float2 hD = *reinterpret_cast<const float2*>(&h[(size_t)(base + lane + 192) * 2]);

    float acc0 = 0.f, acc1 = 0.f;
#pragma unroll 1
    for (int it = 0; it < KNN; ++it) {
        unsigned bv = ua; float bh0 = hA.x, bh1 = hA.y;
        if (ub < bv) { bv = ub; bh0 = hB.x; bh1 = hB.y; }
        if (uc < bv) { bv = uc; bh0 = hC.x; bh1 = hC.y; }
        if (ud < bv) { bv = ud; bh0 = hD.x; bh1 = hD.y; }
        unsigned gv = bv;
#pragma unroll
        for (int m = 1; m < 64; m <<= 1) {
            unsigned o = __shfl_xor(gv, m);
            gv = o < gv ? o : gv;
        }
        float d2 = __uint_as_float(gv);
        if (d2 > 2.0f) break;                    // wave-uniform
        unsigned long long mask = __ballot(bv == gv);
        int wl = __ffsll(mask) - 1;
        if (lane == wl) {
            float w = __expf(-10.0f * d2);
            acc0 = fmaf(w, bh0, acc0);
            acc1 = fmaf(w, bh1, acc1);
            ua = (ua == gv) ? 0xFFFFFFFFu : ua;
            ub = (ub == gv) ? 0xFFFFFFFFu : ub;
            uc = (uc == gv) ? 0xFFFFFFFFu : uc;
            ud = (ud == gv) ? 0xFFFFFFFFu : ud;
        }
    }
#pragma unroll
    for (int m = 1; m < 64; m <<= 1) {
        acc0 += __shfl_xor(acc0, m);
        acc1 += __shfl_xor(acc1, m);
    }
    out0 = acc0; out1 = acc1;
}

__global__ __launch_bounds__(256) void knn_kernel(
    const float* __restrict__ s, const float* __restrict__ h,
    float* __restrict__ agg)
{
    int gw = (int)(blockIdx.x * 4 + (threadIdx.x >> 6));
    int lane = threadIdx.x & 63;
    float a0, a1;
    knn_row_agg(s, h, gw & ~(GN - 1), gw, lane, a0, a1);
    if (lane == 0) {
        agg[gw * 2 + 0] = a0;
        agg[gw * 2 + 1] = a1;
    }
}

// ---------------- MFMA split-bf16 GEMM (no LDS staging) + fused s/h projection ----------
// CMODE 0: C split into Chi/Clo planes [8192][256] (coalesced, via CT); CMODE 1: compact
// fp32 rows m%256==0. Block 512 thr (8 waves, 2m x 4n), BM=64, BN=128. Grid (128, 2).
template<int K, int CMODE>
__global__ __launch_bounds__(512) void gemm_fused(
    const ushort* __restrict__ Ahi, const ushort* __restrict__ Alo,
    const ushort* __restrict__ Bhi, const ushort* __restrict__ Blo,
    const float* __restrict__ Wfull, const float* __restrict__ bias,
    const float* __restrict__ agg,
    float* __restrict__ Cf, ushort* __restrict__ Chi, ushort* __restrict__ Clo,
    const float* __restrict__ Wsn, const float* __restrict__ Whn,
    float* __restrict__ s_out, float* __restrict__ h_out)
{
    __shared__ float CT[64 * CTS];
    __shared__ float part[64 * 8 * 5];

    const int tid = threadIdx.x;
    const int lane = tid & 63, wid = tid >> 6;
    const int wm = wid >> 2, wn = wid & 3;
    const int m0 = blockIdx.x * 64, n0 = blockIdx.y * 128;

    f32x4 acc[2][2];
#pragma unroll
    for (int mi = 0; mi < 2; ++mi)
#pragma unroll
        for (int ni = 0; ni < 2; ++ni)
            acc[mi][ni] = (f32x4){0.f, 0.f, 0.f, 0.f};

#pragma unroll 2
    for (int kof = 0; kof < K; kof += 32) {
        int kch = kof + (lane >> 4) * 8;
        bf16x8 ah[2], al[2], bh[2], bl[2];
#pragma unroll
        for (int mi = 0; mi < 2; ++mi) {
            size_t off = (size_t)(m0 + wm * 32 + mi * 16 + (lane & 15)) * K + kch;
            ah[mi] = ld8(Ahi + off); al[mi] = ld8(Alo + off);
        }
#pragma unroll
        for (int ni = 0; ni < 2; ++ni) {
            size_t off = (size_t)(n0 + wn * 32 + ni * 16 + (lane & 15)) * K + kch;
            bh[ni] = ld8(Bhi + off); bl[ni] = ld8(Blo + off);
        }
#pragma unroll
        for (int mi = 0; mi < 2; ++mi)
#pragma unroll
            for (int ni = 0; ni < 2; ++ni) {
                acc[mi][ni] = __builtin_amdgcn_mfma_f32_16x16x32_bf16(ah[mi], bh[ni], acc[mi][ni], 0, 0, 0);
                acc[mi][ni] = __builtin_amdgcn_mfma_f32_16x16x32_bf16(ah[mi], bl[ni], acc[mi][ni], 0, 0, 0);
                acc[mi][ni] = __builtin_amdgcn_mfma_f32_16x16x32_bf16(al[mi], bh[ni], acc[mi][ni], 0, 0, 0);
            }
    }

    // epilogue: + agg@Wa + bias, leaky, park in CT (C/D map: col=lane&15, row=(lane>>4)*4+r)
#pragma unroll
    for (int ni = 0; ni < 2; ++ni) {
        int nl = wn * 32 + ni * 16 + (lane & 15);
        int n = n0 + nl;
        float w0 = Wfull[n], w1 = Wfull[256 + n], bz = bias[n];
#pragma unroll
        for (int mi = 0; mi < 2; ++mi) {
            int mb = wm * 32 + mi * 16 + ((lane >> 4) << 2);
#pragma unroll
            for (int r = 0; r < 4; ++r) {
                int ml = mb + r, m = m0 + ml;
                float v = acc[mi][ni][r] + fmaf(agg[m * 2 + 0], w0, fmaf(agg[m * 2 + 1], w1, bz));
                v = v >= 0.f ? v : 0.01f * v;
                CT[ml * CTS + nl] = v;
                if (CMODE == 1 && (m & 255) == 0) Cf[(m >> 8) * 256 + n] = v;
            }
        }
    }
    __syncthreads();

    // coalesced C write from CT (CMODE 0): 16 cols/thread, packed uint4 hi/lo
    if (CMODE == 0) {
        int row = tid >> 3, cbase = (tid & 7) * 16;
        size_t m = (size_t)(m0 + row);
#pragma unroll
        for (int j = 0; j < 2; ++j) {
            int c = cbase + j * 8;
            ushort hi[8], lo[8];
#pragma unroll
            for (int t = 0; t < 8; ++t) {
                float v = CT[row * CTS + c + t];
                hi[t] = f2bf(v);
                lo[t] = f2bf(v - bf2f(hi[t]));
            }
            uint4 wh = make_uint4(pack2(hi[0], hi[1]), pack2(hi[2], hi[3]),
                                  pack2(hi[4], hi[5]), pack2(hi[6], hi[7]));
            uint4 wl = make_uint4(pack2(lo[0], lo[1]), pack2(lo[2], lo[3]),
                                  pack2(lo[4], lo[5]), pack2(lo[6], lo[7]));
            *reinterpret_cast<uint4*>(&Chi[m * 256 + n0 + c]) = wh;
            *reinterpret_cast<uint4*>(&Clo[m * 256 + n0 + c]) = wl;
        }
    }

    // phase2: per-row dot with Wsn/Whn over this block's 128 cols.
    // row = tid&63 -> 64 distinct rows per wave -> conflict-free CT reads (stride 129).
    {
        int row = tid & 63, sub = tid >> 6;
        float p0 = 0.f, p1 = 0.f, p2 = 0.f, p3 = 0.f, p4 = 0.f;
#pragma unroll
        for (int i = 0; i < 16; ++i) {
            int c = sub * 16 + i;
            float v = CT[row * CTS + c];
            int n = n0 + c;
            p0 = fmaf(v, Wsn[n * 3 + 0], p0);
            p1 = fmaf(v, Wsn[n * 3 + 1], p1);
            p2 = fmaf(v, Wsn[n * 3 + 2], p2);
            p3 = fmaf(v, Whn[n * 2 + 0], p3);
            p4 = fmaf(v, Whn[n * 2 + 1], p4);
        }
        float* pp = &part[(row * 8 + sub) * 5];
        pp[0] = p0; pp[1] = p1; pp[2] = p2; pp[3] = p3; pp[4] = p4;
    }
    __syncthreads();
    if (tid < 320) {
        int row = tid / 5, o = tid - row * 5;
        float sum = 0.f;
#pragma unroll
        for (int k = 0; k < 8; ++k) sum += part[(row * 8 + k) * 5 + o];
        if (o < 3) atomicAdd(&s_out[(m0 + row) * 3 + o], sum);
        else       atomicAdd(&h_out[(m0 + row) * 2 + (o - 3)], sum);
    }
}

// ---------------- K6: per-graph kNN of row g*256 + final matvec ----------------
__global__ __launch_bounds__(256) void knn3_final(
    const float* __restrict__ s, const float* __restrict__ h,
    const float* __restrict__ h2c,   // [32][256] leaky'd layer-2 rows g*256
    const float* __restrict__ Wo, const float* __restrict__ bo,
    float* __restrict__ out)
{
    __shared__ float aggL[2];
    __shared__ float pm[8][32];
    int g = blockIdx.x, tid = threadIdx.x;
    if (tid < 64) {
        float a0, a1;
        knn_row_agg(s, h, g * GN, g * GN, tid, a0, a1);
        if (tid == 0) { aggL[0] = a0; aggL[1] = a1; }
    }
    __syncthreads();
    int o = tid & 31, seg = tid >> 5;
    const float* xr = h2c + g * 256;
    float p = 0.f;
#pragma unroll
    for (int i = 0; i < 32; ++i) {
        int c = seg * 32 + i;
        p = fmaf(xr[c], Wo[(2 + c) * 32 + o], p);
    }
    pm[seg][o] = p;
    __syncthreads();
    if (tid < 32) {
        float acc = fmaf(aggL[0], Wo[o], fmaf(aggL[1], Wo[32 + o], bo[o]));
#pragma unroll
        for (int k = 0; k < 8; ++k) acc += pm[k][o];
        out[g * 32 + o] = acc;
    }
}

extern "C" void kernel_launch(void* const* d_in, const int* in_sizes, int n_in,
                              void* d_out, int out_size, void* d_ws, size_t ws_size,
                              hipStream_t stream) {
    const float* X   = (const float*)d_in[0];
    const float* Ws1 = (const float*)d_in[2];  const float* bs1 = (const float*)d_in[3];
    const float* Wh1 = (const float*)d_in[4];  const float* bh1 = (const float*)d_in[5];
    const float* Wo1 = (const float*)d_in[6];  const float* bo1 = (const float*)d_in[7];
    const float* Ws2 = (const float*)d_in[8];  const float* bs2 = (const float*)d_in[9];
    const float* Wh2 = (const float*)d_in[10]; const float* bh2 = (const float*)d_in[11];
    const float* Wo2 = (const float*)d_in[12]; const float* bo2 = (const float*)d_in[13];
    const float* Ws3 = (const float*)d_in[14]; const float* bs3 = (const float*)d_in[15];
    const float* Wh3 = (const float*)d_in[16]; const float* bh3 = (const float*)d_in[17];
    const float* Wo3 = (const float*)d_in[18]; const float* bo3 = (const float*)d_in[19];

    float* p = (float*)d_ws;
    float* s1   = p; p += NTOT * 3;
    float* hp1  = p; p += NTOT * 2;
    float* s2   = p; p += NTOT * 3;
    float* hp2  = p; p += NTOT * 2;
    float* s3   = p; p += NTOT * 3;
    float* hp3  = p; p += NTOT * 2;
    float* aggb = p; p += NTOT * 2;
    float* h2c  = p; p += 32 * 256;
    ushort* q = (ushort*)p;
    ushort* Xhi  = q; q += (size_t)NTOT * 64;
    ushort* Xlo  = q; q += (size_t)NTOT * 64;
    ushort* h1hi = q; q += (size_t)NTOT * 256;
    ushort* h1lo = q; q += (size_t)NTOT * 256;
    ushort* Wt1hi = q; q += 256 * 64;
    ushort* Wt1lo = q; q += 256 * 64;
    ushort* Wt2hi = q; q += 256 * 256;
    ushort* Wt2lo = q; q += 256 * 256;

    k_front<<<3712, 256, 0, stream>>>(X, Ws1, bs1, Wh1, bh1, Wo1, Wo2,
                                      bs2, bh2, bs3, bh3,
                                      Wt1hi, Wt1lo, Wt2hi, Wt2lo, Xhi, Xlo,
                                      s1, hp1, s2, hp2, s3, hp3);
    knn_kernel<<<2048, 256, 0, stream>>>(s1, hp1, aggb);
    gemm_fused<64, 0><<<dim3(128, 2), 512, 0, stream>>>(Xhi, Xlo, Wt1hi, Wt1lo,
                                                        Wo1, bo1, aggb,
                                                        nullptr, h1hi, h1lo,
                                                        Ws2, Wh2, s2, hp2);
    knn_kernel<<<2048, 256, 0, stream>>>(s2, hp2, aggb);
    gemm_fused<256, 1><<<dim3(128, 2), 512, 0, stream>>>(h1hi, h1lo, Wt2hi, Wt2lo,
                                                         Wo2, bo2, aggb,
                                                         h2c, nullptr, nullptr,
                                                         Ws3, Wh3, s3, hp3);
    knn3_final<<<NGRAPH, 256, 0, stream>>>(s3, hp3, h2c, Wo3, bo3, (float*)d_out);
}

// Round 6
// 78.774 us; speedup vs baseline: 1.7384x; 1.0154x over previous
//
#include <hip/hip_runtime.h>
#include <hip/hip_bf16.h>

// GravNet: 32 graphs x 256 nodes, IN=64, HID=256, OUT=32, K=20, SPACE=3, PROP=2
// 5-launch pipeline:
//  K1 knn1_mega : [b<512] in-block sh1 (LDS) + layer-1 kNN+agg | [512..832) weight split
//                 | [832..1152) bias-init s/h bufs | [1152..2176) X hi/lo split
//  K2 gemm<64,0>: h1(split bf16 planes) = leaky([agg,X]@Wo1+bo1) + fused s2/h2 partials
//  K3 knn2      : layer-2 kNN+aggregate (global s2/h2)
//  K4 gemm<256,1>: h2 compact rows g*256 + fused s3/h3 partials
//  K5 knn3_final: per-graph kNN of row g*256 + final 258->32 matvec
// All wave reductions use DPP (row_shr/bcast + readlane) -> zero LDS-pipe traffic.
// GEMM x-part: split-bf16 MFMA (hi/lo, 3 products) == fp32 precision, no LDS staging.

#define NGRAPH 32
#define GN 256
#define NTOT (NGRAPH*GN) // 8192
#define KNN 20
#define CTS 129          // CT leading dim (floats) — breaks LDS bank aliasing

typedef __attribute__((ext_vector_type(8))) short bf16x8;
typedef __attribute__((ext_vector_type(4))) float f32x4;

__device__ __forceinline__ ushort f2bf(float x) {
    union { float f; unsigned u; } a; a.f = x;
    unsigned r = a.u + 0x7FFFu + ((a.u >> 16) & 1u);   // RNE
    return (ushort)(r >> 16);
}
__device__ __forceinline__ float bf2f(ushort h) {
    union { unsigned u; float f; } b; b.u = ((unsigned)h) << 16;
    return b.f;
}
__device__ __forceinline__ bf16x8 ld8(const ushort* p) {
    return *reinterpret_cast<const bf16x8*>(p);
}
__device__ __forceinline__ unsigned pack2(ushort a, ushort b) {
    return (unsigned)a | ((unsigned)b << 16);
}

// ---- DPP wave reductions (VALU-only, no LDS pipe) ----
#define DPP_MIN(v, ctrl, rmask) { \
    unsigned _t = (unsigned)__builtin_amdgcn_update_dpp((int)(v), (int)(v), ctrl, rmask, 0xf, false); \
    (v) = _t < (v) ? _t : (v); }
__device__ __forceinline__ unsigned wave_min_u32(unsigned v) {
    DPP_MIN(v, 0x111, 0xf)   // row_shr:1
    DPP_MIN(v, 0x112, 0xf)   // row_shr:2
    DPP_MIN(v, 0x114, 0xf)   // row_shr:4
    DPP_MIN(v, 0x118, 0xf)   // row_shr:8
    DPP_MIN(v, 0x142, 0xa)   // bcast15 -> rows 1,3
    DPP_MIN(v, 0x143, 0xc)   // bcast31 -> rows 2,3
    return (unsigned)__builtin_amdgcn_readlane((int)v, 63);   // wave-uniform
}
#define DPP_ADD(v, ctrl, rmask) { \
    float _t = __int_as_float(__builtin_amdgcn_update_dpp(0, __float_as_int(v), ctrl, rmask, 0xf, true)); \
    (v) += _t; }
__device__ __forceinline__ float wave_sum_f32(float v) {
    DPP_ADD(v, 0x111, 0xf)
    DPP_ADD(v, 0x112, 0xf)
    DPP_ADD(v, 0x114, 0xf)
    DPP_ADD(v, 0x118, 0xf)
    DPP_ADD(v, 0x142, 0xa)
    DPP_ADD(v, 0x143, 0xc)
    return __int_as_float(__builtin_amdgcn_readlane(__float_as_int(v), 63));
}

// ---- kNN top-20 extraction core: keys = d2 bits (>=0 so u32 order == float order) ----
// Winner = lowest lane holding the wave-min (cross-lane exact-bit ties: measure-zero).
// Early exit when min d2 > 2.0 (residual weights < 2e-9).
__device__ __forceinline__ void knn_extract(
    unsigned ua, unsigned ub, unsigned uc, unsigned ud,
    float2 hA, float2 hB, float2 hC, float2 hD,
    int lane, float& out0, float& out1)
{
    float acc0 = 0.f, acc1 = 0.f;
#pragma unroll 1
    for (int it = 0; it < KNN; ++it) {
        unsigned m1 = ua < ub ? ua : ub;
        unsigned m2 = uc < ud ? uc : ud;
        unsigned bv = m1 < m2 ? m1 : m2;
        unsigned gv = wave_min_u32(bv);
        float d2 = __uint_as_float(gv);
        if (d2 > 2.0f) break;                        // wave-uniform (gv is SGPR)
        float w = __expf(-10.0f * d2);
        unsigned long long mask = __ballot(bv == gv);
        int wl = __ffsll(mask) - 1;
        if (lane == wl) {
            float h0, h1;
            if (ua == gv)      { h0 = hA.x; h1 = hA.y; ua = 0xFFFFFFFFu; }
            else if (ub == gv) { h0 = hB.x; h1 = hB.y; ub = 0xFFFFFFFFu; }
            else if (uc == gv) { h0 = hC.x; h1 = hC.y; uc = 0xFFFFFFFFu; }
            else               { h0 = hD.x; h1 = hD.y; ud = 0xFFFFFFFFu; }
            acc0 = fmaf(w, h0, acc0);
            acc1 = fmaf(w, h1, acc1);
        }
    }
    out0 = wave_sum_f32(acc0);
    out1 = wave_sum_f32(acc1);
}

// ---------------- K1: in-block sh1 + knn1 | prep | init | Xsplit ----------------
__global__ __launch_bounds__(256) void knn1_mega(
    const float* __restrict__ X,
    const float* __restrict__ Ws1, const float* __restrict__ bs1,
    const float* __restrict__ Wh1, const float* __restrict__ bh1,
    const float* __restrict__ Wo1, const float* __restrict__ Wo2,
    const float* __restrict__ bs2, const float* __restrict__ bh2,
    const float* __restrict__ bs3, const float* __restrict__ bh3,
    ushort* __restrict__ Wt1hi, ushort* __restrict__ Wt1lo,
    ushort* __restrict__ Wt2hi, ushort* __restrict__ Wt2lo,
    ushort* __restrict__ Xhi, ushort* __restrict__ Xlo,
    float* __restrict__ s2, float* __restrict__ h2p,
    float* __restrict__ s3, float* __restrict__ h3p,
    float* __restrict__ agg)
{
    __shared__ float sh5[256 * 5];    // s(3) + h(2) per node, stride 5 (coprime 32 banks)
    int b = blockIdx.x, tid = threadIdx.x;
    if (b < 512) {                    // ---- sh1 (whole graph, redundant x16) + knn (16 rows)
        int g = b >> 4;
        const float* Xg = X + (size_t)g * (GN * 64);
        {
            float a0 = 0.f, a1 = 0.f, a2 = 0.f, a3 = 0.f, a4 = 0.f;
            const float* xr = Xg + tid * 64;
#pragma unroll 4
            for (int c0 = 0; c0 < 64; c0 += 4) {
                float4 v = *reinterpret_cast<const float4*>(&xr[c0]);
                float xv[4] = {v.x, v.y, v.z, v.w};
#pragma unroll
                for (int j = 0; j < 4; ++j) {
                    int c = c0 + j;
                    a0 = fmaf(xv[j], Ws1[c * 3 + 0], a0);
                    a1 = fmaf(xv[j], Ws1[c * 3 + 1], a1);
                    a2 = fmaf(xv[j], Ws1[c * 3 + 2], a2);
                    a3 = fmaf(xv[j], Wh1[c * 2 + 0], a3);
                    a4 = fmaf(xv[j], Wh1[c * 2 + 1], a4);
                }
            }
            sh5[tid * 5 + 0] = a0 + bs1[0];
            sh5[tid * 5 + 1] = a1 + bs1[1];
            sh5[tid * 5 + 2] = a2 + bs1[2];
            sh5[tid * 5 + 3] = a3 + bh1[0];
            sh5[tid * 5 + 4] = a4 + bh1[1];
        }
        __syncthreads();
        int lane = tid & 63, wid = tid >> 6;
        float sjx[4], sjy[4], sjz[4], s2j[4];
        float2 hs[4];
#pragma unroll
        for (int t = 0; t < 4; ++t) {
            int j = lane + 64 * t;
            float x = sh5[j * 5 + 0], y = sh5[j * 5 + 1], z = sh5[j * 5 + 2];
            sjx[t] = x; sjy[t] = y; sjz[t] = z;
            s2j[t] = x * x + y * y + z * z;
            hs[t] = make_float2(sh5[j * 5 + 3], sh5[j * 5 + 4]);
        }
        int rbase = (b & 15) * 16 + wid * 4;
#pragma unroll 1
        for (int rr = 0; rr < 4; ++rr) {
            int rl = rbase + rr;
            float s0 = sh5[rl * 5 + 0], s1v = sh5[rl * 5 + 1], s2v = sh5[rl * 5 + 2];
            float s2row = s0 * s0 + s1v * s1v + s2v * s2v;
            unsigned key[4];
#pragma unroll
            for (int t = 0; t < 4; ++t) {
                float dot = s0 * sjx[t] + s1v * sjy[t] + s2v * sjz[t];
                float d2 = s2row + s2j[t] - 2.0f * dot;
                key[t] = __float_as_uint(d2 > 0.f ? d2 : 0.f);
            }
            float a0, a1;
            knn_extract(key[0], key[1], key[2], key[3], hs[0], hs[1], hs[2], hs[3], lane, a0, a1);
            if (lane == 0) {
                agg[(g * GN + rl) * 2 + 0] = a0;
                agg[(g * GN + rl) * 2 + 1] = a1;
            }
        }
    } else if (b < 832) {             // ---- prep: Wo[2+c][n] -> Wt[n][c] hi/lo
        int t = (b - 512) * 256 + tid;
        if (t < 65536) {
            int n = t >> 8, c = t & 255;
            float v = Wo2[(size_t)(2 + c) * 256 + n];
            ushort hi = f2bf(v);
            Wt2hi[n * 256 + c] = hi;
            Wt2lo[n * 256 + c] = f2bf(v - bf2f(hi));
        } else {
            int u = t - 65536;
            int n = u >> 6, c = u & 63;
            float v = Wo1[(size_t)(2 + c) * 256 + n];
            ushort hi = f2bf(v);
            Wt1hi[n * 64 + c] = hi;
            Wt1lo[n * 64 + c] = f2bf(v - bf2f(hi));
        }
    } else if (b < 1152) {            // ---- init s2/h2/s3/h3 with biases
        int u = (b - 832) * 256 + tid;   // 0..81919
        if (u < 24576)      s2[u] = bs2[u % 3];
        else if (u < 40960) { int w = u - 24576; h2p[w] = bh2[w & 1]; }
        else if (u < 65536) { int w = u - 40960; s3[w] = bs3[w % 3]; }
        else                { int w = u - 65536; h3p[w] = bh3[w & 1]; }
    } else {                          // ---- X hi/lo split: 2 floats/thread
        int t = (b - 1152) * 256 + tid;  // 0..262143
        float2 v = *reinterpret_cast<const float2*>(&X[(size_t)t * 2]);
        ushort hx = f2bf(v.x), hy = f2bf(v.y);
        Xhi[t * 2 + 0] = hx; Xlo[t * 2 + 0] = f2bf(v.x - bf2f(hx));
        Xhi[t * 2 + 1] = hy; Xlo[t * 2 + 1] = f2bf(v.y - bf2f(hy));
    }
}

// ---------------- knn (layers 2): one wave per row, global s/h ----------------
__global__ __launch_bounds__(256) void knn_kernel(
    const float* __restrict__ s, const float* __restrict__ h,
    float* __restrict__ agg)
{
    int gw = (int)(blockIdx.x * 4 + (threadIdx.x >> 6));
    int lane = threadIdx.x & 63;
    int base = gw & ~(GN - 1);
    float s0 = s[gw * 3 + 0], s1v = s[gw * 3 + 1], s2v = s[gw * 3 + 2];
    float s2row = s0 * s0 + s1v * s1v + s2v * s2v;
    unsigned key[4]; float2 hs[4];
#pragma unroll
    for (int t = 0; t < 4; ++t) {
        int j = base + lane + 64 * t;
        float x = s[j * 3 + 0], y = s[j * 3 + 1], z = s[j * 3 + 2];
        float dot = s0 * x + s1v * y + s2v * z;
        float d2 = s2row + (x * x + y * y + z * z) - 2.0f * dot;
        key[t] = __float_as_uint(d2 > 0.f ? d2 : 0.f);
        hs[t] = *reinterpret_cast<const float2*>(&h[(size_t)j * 2]);
    }
    float a0, a1;
    knn_extract(key[0], key[1], key[2], key[3], hs[0], hs[1], hs[2], hs[3], lane, a0, a1);
    if (lane == 0) {
        agg[gw * 2 + 0] = a0;
        agg[gw * 2 + 1] = a1;
    }
}

// ---------------- MFMA split-bf16 GEMM (no LDS staging) + fused s/h projection ----------
// CMODE 0: C split into Chi/Clo planes [8192][256] (coalesced, via CT); CMODE 1: compact
// fp32 rows m%256==0. Block 512 thr (8 waves, 2m x 4n), BM=64, BN=128. Grid (128, 2).
template<int K, int CMODE>
__global__ __launch_bounds__(512) void gemm_fused(
    const ushort* __restrict__ Ahi, const ushort* __restrict__ Alo,
    const ushort* __restrict__ Bhi, const ushort* __restrict__ Blo,
    const float* __restrict__ Wfull, const float* __restrict__ bias,
    const float* __restrict__ agg,
    float* __restrict__ Cf, ushort* __restrict__ Chi, ushort* __restrict__ Clo,
    const float* __restrict__ Wsn, const float* __restrict__ Whn,
    float* __restrict__ s_out, float* __restrict__ h_out)
{
    __shared__ float CT[64 * CTS];
    __shared__ float part[64 * 8 * 5];

    const int tid = threadIdx.x;
    const int lane = tid & 63, wid = tid >> 6;
    const int wm = wid >> 2, wn = wid & 3;
    const int m0 = blockIdx.x * 64, n0 = blockIdx.y * 128;

    f32x4 acc[2][2];
#pragma unroll
    for (int mi = 0; mi < 2; ++mi)
#pragma unroll
        for (int ni = 0; ni < 2; ++ni)
            acc[mi][ni] = (f32x4){0.f, 0.f, 0.f, 0.f};

#pragma unroll 2
    for (int kof = 0; kof < K; kof += 32) {
        int kch = kof + (lane >> 4) * 8;
        bf16x8 ah[2], al[2], bh[2], bl[2];
#pragma unroll
        for (int mi = 0; mi < 2; ++mi) {
            size_t off = (size_t)(m0 + wm * 32 + mi * 16 + (lane & 15)) * K + kch;
            ah[mi] = ld8(Ahi + off); al[mi] = ld8(Alo + off);
        }
#pragma unroll
        for (int ni = 0; ni < 2; ++ni) {
            size_t off = (size_t)(n0 + wn * 32 + ni * 16 + (lane & 15)) * K + kch;
            bh[ni] = ld8(Bhi + off); bl[ni] = ld8(Blo + off);
        }
#pragma unroll
        for (int mi = 0; mi < 2; ++mi)
#pragma unroll
            for (int ni = 0; ni < 2; ++ni) {
                acc[mi][ni] = __builtin_amdgcn_mfma_f32_16x16x32_bf16(ah[mi], bh[ni], acc[mi][ni], 0, 0, 0);
                acc[mi][ni] = __builtin_amdgcn_mfma_f32_16x16x32_bf16(ah[mi], bl[ni], acc[mi][ni], 0, 0, 0);
                acc[mi][ni] = __builtin_amdgcn_mfma_f32_16x16x32_bf16(al[mi], bh[ni], acc[mi][ni], 0, 0, 0);
            }
    }

    // epilogue: + agg@Wa + bias, leaky, park in CT (C/D map: col=lane&15, row=(lane>>4)*4+r)
#pragma unroll
    for (int ni = 0; ni < 2; ++ni) {
        int nl = wn * 32 + ni * 16 + (lane & 15);
        int n = n0 + nl;
        float w0 = Wfull[n], w1 = Wfull[256 + n], bz = bias[n];
#pragma unroll
        for (int mi = 0; mi < 2; ++mi) {
            int mb = wm * 32 + mi * 16 + ((lane >> 4) << 2);
#pragma unroll
            for (int r = 0; r < 4; ++r) {
                int ml = mb + r, m = m0 + ml;
                float v = acc[mi][ni][r] + fmaf(agg[m * 2 + 0], w0, fmaf(agg[m * 2 + 1], w1, bz));
                v = v >= 0.f ? v : 0.01f * v;
                CT[ml * CTS + nl] = v;
                if (CMODE == 1 && (m & 255) == 0) Cf[(m >> 8) * 256 + n] = v;
            }
        }
    }
    __syncthreads();

    // coalesced C write from CT (CMODE 0): 16 cols/thread, packed uint4 hi/lo
    if (CMODE == 0) {
        int row = tid >> 3, cbase = (tid & 7) * 16;
        size_t m = (size_t)(m0 + row);
#pragma unroll
        for (int j = 0; j < 2; ++j) {
            int c = cbase + j * 8;
            ushort hi[8], lo[8];
#pragma unroll
            for (int t = 0; t < 8; ++t) {
                float v = CT[row * CTS + c + t];
                hi[t] = f2bf(v);
                lo[t] = f2bf(v - bf2f(hi[t]));
            }
            uint4 wh = make_uint4(pack2(hi[0], hi[1]), pack2(hi[2], hi[3]),
                                  pack2(hi[4], hi[5]), pack2(hi[6], hi[7]));
            uint4 wl = make_uint4(pack2(lo[0], lo[1]), pack2(lo[2], lo[3]),
                                  pack2(lo[4], lo[5]), pack2(lo[6], lo[7]));
            *reinterpret_cast<uint4*>(&Chi[m * 256 + n0 + c]) = wh;
            *reinterpret_cast<uint4*>(&Clo[m * 256 + n0 + c]) = wl;
        }
    }

    // phase2: per-row dot with Wsn/Whn over this block's 128 cols.
    {
        int row = tid & 63, sub = tid >> 6;
        float p0 = 0.f, p1 = 0.f, p2 = 0.f, p3 = 0.f, p4 = 0.f;
#pragma unroll
        for (int i = 0; i < 16; ++i) {
            int c = sub * 16 + i;
            float v = CT[row * CTS + c];
            int n = n0 + c;
            p0 = fmaf(v, Wsn[n * 3 + 0], p0);
            p1 = fmaf(v, Wsn[n * 3 + 1], p1);
            p2 = fmaf(v, Wsn[n * 3 + 2], p2);
            p3 = fmaf(v, Whn[n * 2 + 0], p3);
            p4 = fmaf(v, Whn[n * 2 + 1], p4);
        }
        float* pp = &part[(row * 8 + sub) * 5];
        pp[0] = p0; pp[1] = p1; pp[2] = p2; pp[3] = p3; pp[4] = p4;
    }
    __syncthreads();
    if (tid < 320) {
        int row = tid / 5, o = tid - row * 5;
        float sum = 0.f;
#pragma unroll
        for (int k = 0; k < 8; ++k) sum += part[(row * 8 + k) * 5 + o];
        if (o < 3) atomicAdd(&s_out[(m0 + row) * 3 + o], sum);
        else       atomicAdd(&h_out[(m0 + row) * 2 + (o - 3)], sum);
    }
}

// ---------------- K5: per-graph kNN of row g*256 + final matvec ----------------
__global__ __launch_bounds__(256) void knn3_final(
    const float* __restrict__ s, const float* __restrict__ h,
    const float* __restrict__ h2c,   // [32][256] leaky'd layer-2 rows g*256
    const float* __restrict__ Wo, const float* __restrict__ bo,
    float* __restrict__ out)
{
    __shared__ float aggL[2];
    __shared__ float pm[8][32];
    int g = blockIdx.x, tid = threadIdx.x;
    if (tid < 64) {
        int lane = tid;
        int base = g * GN, row = g * GN;
        float s0 = s[row * 3 + 0], s1v = s[row * 3 + 1], s2v = s[row * 3 + 2];
        float s2row = s0 * s0 + s1v * s1v + s2v * s2v;
        unsigned key[4]; float2 hs[4];
#pragma unroll
        for (int t = 0; t < 4; ++t) {
            int j = base + lane + 64 * t;
            float x = s[j * 3 + 0], y = s[j * 3 + 1], z = s[j * 3 + 2];
            float dot = s0 * x + s1v * y + s2v * z;
            float d2 = s2row + (x * x + y * y + z * z) - 2.0f * dot;
            key[t] = __float_as_uint(d2 > 0.f ? d2 : 0.f);
            hs[t] = *reinterpret_cast<const float2*>(&h[(size_t)j * 2]);
        }
        float a0, a1;
        knn_extract(key[0], key[1], key[2], key[3], hs[0], hs[1], hs[2], hs[3], lane, a0, a1);
        if (lane == 0) { aggL[0] = a0; aggL[1] = a1; }
    }
    __syncthreads();
    int o = tid & 31, seg = tid >> 5;
    const float* xr = h2c + g * 256;
    float p = 0.f;
#pragma unroll
    for (int i = 0; i < 32; ++i) {
        int c = seg * 32 + i;
        p = fmaf(xr[c], Wo[(2 + c) * 32 + o], p);
    }
    pm[seg][o] = p;
    __syncthreads();
    if (tid < 32) {
        float acc = fmaf(aggL[0], Wo[o], fmaf(aggL[1], Wo[32 + o], bo[o]));
#pragma unroll
        for (int k = 0; k < 8; ++k) acc += pm[k][o];
        out[g * 32 + o] = acc;
    }
}

extern "C" void kernel_launch(void* const* d_in, const int* in_sizes, int n_in,
                              void* d_out, int out_size, void* d_ws, size_t ws_size,
                              hipStream_t stream) {
    const float* X   = (const float*)d_in[0];
    const float* Ws1 = (const float*)d_in[2];  const float* bs1 = (const float*)d_in[3];
    const float* Wh1 = (const float*)d_in[4];  const float* bh1 = (const float*)d_in[5];
    const float* Wo1 = (const float*)d_in[6];  const float* bo1 = (const float*)d_in[7];
    const float* Ws2 = (const float*)d_in[8];  const float* bs2 = (const float*)d_in[9];
    const float* Wh2 = (const float*)d_in[10]; const float* bh2 = (const float*)d_in[11];
    const float* Wo2 = (const float*)d_in[12]; const float* bo2 = (const float*)d_in[13];
    const float* Ws3 = (const float*)d_in[14]; const float* bs3 = (const float*)d_in[15];
    const float* Wh3 = (const float*)d_in[16]; const float* bh3 = (const float*)d_in[17];
    const float* Wo3 = (const float*)d_in[18]; const float* bo3 = (const float*)d_in[19];

    float* p = (float*)d_ws;
    float* s2   = p; p += NTOT * 3;
    float* hp2  = p; p += NTOT * 2;
    float* s3   = p; p += NTOT * 3;
    float* hp3  = p; p += NTOT * 2;
    float* aggb = p; p += NTOT * 2;
    float* h2c  = p; p += 32 * 256;
    ushort* q = (ushort*)p;
    ushort* Xhi  = q; q += (size_t)NTOT * 64;
    ushort* Xlo  = q; q += (size_t)NTOT * 64;
    ushort* h1hi = q; q += (size_t)NTOT * 256;
    ushort* h1lo = q; q += (size_t)NTOT * 256;
    ushort* Wt1hi = q; q += 256 * 64;
    ushort* Wt1lo = q; q += 256 * 64;
    ushort* Wt2hi = q; q += 256 * 256;
    ushort* Wt2lo = q; q += 256 * 256;

    knn1_mega<<<2176, 256, 0, stream>>>(X, Ws1, bs1, Wh1, bh1, Wo1, Wo2,
                                        bs2, bh2, bs3, bh3,
                                        Wt1hi, Wt1lo, Wt2hi, Wt2lo, Xhi, Xlo,
                                        s2, hp2, s3, hp3, aggb);
    gemm_fused<64, 0><<<dim3(128, 2), 512, 0, stream>>>(Xhi, Xlo, Wt1hi, Wt1lo,
                                                        Wo1, bo1, aggb,
                                                        nullptr, h1hi, h1lo,
                                                        Ws2, Wh2, s2, hp2);
    knn_kernel<<<2048, 256, 0, stream>>>(s2, hp2, aggb);
    gemm_fused<256, 1><<<dim3(128, 2), 512, 0, stream>>>(h1hi, h1lo, Wt2hi, Wt2lo,
                                                         Wo2, bo2, aggb,
                                                         h2c, nullptr, nullptr,
                                                         Ws3, Wh3, s3, hp3);
    knn3_final<<<NGRAPH, 256, 0, stream>>>(s3, hp3, h2c, Wo3, bo3, (float*)d_out);
}